// Round 14
// baseline (445.910 us; speedup 1.0000x reference)
//
#include <hip/hip_runtime.h>
#include <hip/hip_bf16.h>
#include <math.h>

#define HH 32
#define NODE_IN 64
#define EDGE_IN 16
#define EDGE_H 128
#define M_TILE 256   // edges per block in MFMA edge kernel (8 waves x 32 edges)

typedef __attribute__((ext_vector_type(8))) short bf16x8;
typedef __attribute__((ext_vector_type(4))) float f32x4;

__device__ inline unsigned short f2bf(float f) {
    union { float f; unsigned int u; } v; v.f = f;
    unsigned int r = v.u + 0x7fff + ((v.u >> 16) & 1);   // RNE (inputs never NaN)
    return (unsigned short)(r >> 16);
}

__device__ inline void gload_lds16(const void* g, void* lds) {
    __builtin_amdgcn_global_load_lds(
        (const __attribute__((address_space(1))) void*)g,
        (__attribute__((address_space(3))) void*)lds, 16, 0, 0);
}

// ---------------- prep: W2 f32 -> bf16, CHUNK-SWIZZLED global layout ----------------
__global__ void k_prep_w2(const float* __restrict__ en2_w, unsigned short* __restrict__ W2s) {
    int i = blockIdx.x * 256 + threadIdx.x;
    int r = i >> 7, q = i & 127;
    int p = q >> 3, sub = q & 7;
    int c = p ^ (r & 15);
    W2s[i] = f2bf(en2_w[r * EDGE_H + c * 8 + sub]);
}

// ---------------- prep: R = relu(e_feat @ en1_w^T + en1_b) -> bf16 [E_pad][128] ----------------
__global__ void __launch_bounds__(256, 4)
k_prep_r(const float* __restrict__ e_feat, const float* __restrict__ en1_w,
         const float* __restrict__ en1_b, unsigned short* __restrict__ Rb,
         int E, int E_pad) {
    int t = threadIdx.x, wave = t >> 6, l = t & 63;
    int lo = l & 15, lq = l >> 4;
    int ebase = blockIdx.x * 256 + wave * 64;

    bf16x8 bfrag[8];
    #pragma unroll
    for (int nt = 0; nt < 8; ++nt) {
        unsigned short br[8] = {0, 0, 0, 0, 0, 0, 0, 0};
        if (lq < 2) {
            const float* wr = en1_w + (nt * 16 + lo) * EDGE_IN + lq * 8;
            #pragma unroll
            for (int z = 0; z < 8; ++z) br[z] = f2bf(wr[z]);
        }
        bfrag[nt] = *(const bf16x8*)br;
    }
    float b1v[8];
    #pragma unroll
    for (int nt = 0; nt < 8; ++nt) b1v[nt] = en1_b[nt * 16 + lo];

    #pragma unroll
    for (int m = 0; m < 4; ++m) {
        int ea = ebase + m * 16 + lo;
        unsigned short ar[8] = {0, 0, 0, 0, 0, 0, 0, 0};
        if (lq < 2 && ea < E) {
            const float* er = e_feat + (size_t)ea * EDGE_IN + lq * 8;
            float4 v0 = ((const float4*)er)[0];
            float4 v1 = ((const float4*)er)[1];
            ar[0] = f2bf(v0.x); ar[1] = f2bf(v0.y); ar[2] = f2bf(v0.z); ar[3] = f2bf(v0.w);
            ar[4] = f2bf(v1.x); ar[5] = f2bf(v1.y); ar[6] = f2bf(v1.z); ar[7] = f2bf(v1.w);
        }
        bf16x8 af = *(const bf16x8*)ar;

        int erow = ebase + m * 16 + lq * 4;
        #pragma unroll
        for (int nt = 0; nt < 8; ++nt) {
            f32x4 acc = (f32x4){b1v[nt], b1v[nt], b1v[nt], b1v[nt]};
            acc = __builtin_amdgcn_mfma_f32_16x16x32_bf16(af, bfrag[nt], acc, 0, 0, 0);
            #pragma unroll
            for (int r = 0; r < 4; ++r)
                Rb[(size_t)(erow + r) * EDGE_H + nt * 16 + lo] = f2bf(fmaxf(acc[r], 0.f));
        }
    }
}

// ---------------- lin0 ----------------
__global__ void k_lin0(const float* __restrict__ nf, const float* __restrict__ w,
                       const float* __restrict__ b, float* __restrict__ out,
                       float* __restrict__ h0, int n) {
    __shared__ float nf_s[8][NODE_IN];
    __shared__ float w_s[HH][NODE_IN + 1];
    int t = threadIdx.x;
    for (int i = t; i < HH * NODE_IN; i += 256) w_s[i / NODE_IN][i % NODE_IN] = w[i];
    int n0 = blockIdx.x * 8;
    for (int i = t; i < 8 * NODE_IN; i += 256) {
        int nl = i / NODE_IN, k = i % NODE_IN;
        int nn = n0 + nl;
        nf_s[nl][k] = (nn < n) ? nf[(size_t)nn * NODE_IN + k] : 0.f;
    }
    __syncthreads();
    int nl = t >> 5, h = t & 31;
    int nn = n0 + nl;
    if (nn < n) {
        float acc = b[h];
        #pragma unroll
        for (int k = 0; k < NODE_IN; ++k) acc += nf_s[nl][k] * w_s[h][k];
        acc = fmaxf(acc, 0.f);
        out[(size_t)nn * HH + h] = acc;
        h0[(size_t)nn * HH + h] = acc;
    }
}

// ---------------- CSR build (by dst) ----------------
__global__ void k_zero_int(int* __restrict__ p, int n) {
    int i = blockIdx.x * 256 + threadIdx.x;
    if (i < n) p[i] = 0;
}
__global__ void k_hist(const int* __restrict__ dst, int* __restrict__ deg, int E) {
    int e = blockIdx.x * 256 + threadIdx.x;
    if (e < E) atomicAdd(&deg[dst[e]], 1);
}
__global__ void k_scan1(const int* __restrict__ deg, int* __restrict__ offtmp,
                        int* __restrict__ bsum, int n) {
    __shared__ int sh[256];
    int tid = threadIdx.x;
    int i = blockIdx.x * 256 + tid;
    int v = (i < n) ? deg[i] : 0;
    sh[tid] = v;
    __syncthreads();
    for (int d = 1; d < 256; d <<= 1) {
        int add = (tid >= d) ? sh[tid - d] : 0;
        __syncthreads();
        sh[tid] += add;
        __syncthreads();
    }
    if (i < n) offtmp[i] = sh[tid] - v;
    if (tid == 255) bsum[blockIdx.x] = sh[255];
}
__global__ void k_scan2(int* __restrict__ bsum, int nb) {
    __shared__ int sh[256];
    int tid = threadIdx.x;
    int v = (tid < nb) ? bsum[tid] : 0;
    sh[tid] = v;
    __syncthreads();
    for (int d = 1; d < 256; d <<= 1) {
        int add = (tid >= d) ? sh[tid - d] : 0;
        __syncthreads();
        sh[tid] += add;
        __syncthreads();
    }
    if (tid < nb) bsum[tid] = sh[tid] - v;
}
__global__ void k_scan3(const int* __restrict__ offtmp, const int* __restrict__ bsum,
                        int* __restrict__ offsets, int* __restrict__ cursor, int n, int E) {
    int i = blockIdx.x * 256 + threadIdx.x;
    if (i < n) { offsets[i] = offtmp[i] + bsum[i >> 8]; cursor[i] = 0; }
    if (i == n) offsets[n] = E;
}
__global__ void k_scatter_pos(const int* __restrict__ dst, const int* __restrict__ offsets,
                              int* __restrict__ cursor, int* __restrict__ pos, int E) {
    int e = blockIdx.x * 256 + threadIdx.x;
    if (e < E) pos[e] = offsets[dst[e]] + atomicAdd(&cursor[dst[e]], 1);
}

// ---------------- MFMA edge kernel v4 (proven best: 51us) ----------------
__global__ void __launch_bounds__(512, 2)
k_edge_mfma4(const unsigned short* __restrict__ Rb, const unsigned short* __restrict__ W2s,
             const float* __restrict__ b2, const float* __restrict__ cur,
             const int* __restrict__ src, const int* __restrict__ pos,
             float* __restrict__ outp, int E) {
    __shared__ unsigned short w2buf[4][32 * EDGE_H];
    __shared__ float x_t[HH][M_TILE];
    __shared__ float b2_s[HH * HH];
    int t = threadIdx.x, wave = t >> 6, l = t & 63;
    int lo = l & 15, lq = l >> 4;
    int e0 = blockIdx.x * M_TILE;

    for (int i = t; i < HH * HH; i += 512) b2_s[i] = b2[i];

    for (int i = t; i < M_TILE * 8; i += 512) {
        int el = i >> 3, c = i & 7;
        int e = e0 + el;
        float4 v = make_float4(0.f, 0.f, 0.f, 0.f);
        if (e < E) v = ((const float4*)(cur + (size_t)src[e] * HH))[c];
        x_t[c * 4 + 0][el] = v.x; x_t[c * 4 + 1][el] = v.y;
        x_t[c * 4 + 2][el] = v.z; x_t[c * 4 + 3][el] = v.w;
    }

    bf16x8 afrag[2][4];
    #pragma unroll
    for (int m = 0; m < 2; ++m)
        #pragma unroll
        for (int ks = 0; ks < 4; ++ks)
            afrag[m][ks] = *(const bf16x8*)(Rb + (size_t)(e0 + wave * 32 + m * 16 + lo) * EDGE_H + ks * 32 + lq * 8);

    #pragma unroll
    for (int s = 0; s < 3; ++s)
        gload_lds16(W2s + (size_t)s * 4096 + t * 8, &w2buf[s][t * 8]);

    asm volatile("s_waitcnt lgkmcnt(0)" ::: "memory");

    float macc[2][2][4];
    #pragma unroll
    for (int m = 0; m < 2; ++m)
        #pragma unroll
        for (int nn = 0; nn < 2; ++nn)
            #pragma unroll
            for (int r = 0; r < 4; ++r) macc[m][nn][r] = 0.f;

    #pragma unroll 4
    for (int h = 0; h < HH; ++h) {
        if (h < 30)       asm volatile("s_waitcnt vmcnt(2)" ::: "memory");
        else if (h == 30) asm volatile("s_waitcnt vmcnt(1)" ::: "memory");
        else              asm volatile("s_waitcnt vmcnt(0)" ::: "memory");
        __builtin_amdgcn_s_barrier();
        if (h + 3 < HH)
            gload_lds16(W2s + (size_t)(h + 3) * 4096 + t * 8, &w2buf[(h + 3) & 3][t * 8]);

        const unsigned short* wb = w2buf[h & 3];
        bf16x8 bfrag[2][4];
        #pragma unroll
        for (int nn = 0; nn < 2; ++nn)
            #pragma unroll
            for (int ks = 0; ks < 4; ++ks)
                bfrag[nn][ks] = *(const bf16x8*)&wb[(nn * 16 + lo) * EDGE_H + (((ks * 4 + lq) ^ lo) * 8)];

        f32x4 acc[2][2];
        #pragma unroll
        for (int nn = 0; nn < 2; ++nn) {
            float bb = b2_s[h * HH + nn * 16 + lo];
            acc[0][nn] = (f32x4){bb, bb, bb, bb};
            acc[1][nn] = (f32x4){bb, bb, bb, bb};
        }
        #pragma unroll
        for (int ks = 0; ks < 4; ++ks)
            #pragma unroll
            for (int m = 0; m < 2; ++m)
                #pragma unroll
                for (int nn = 0; nn < 2; ++nn)
                    acc[m][nn] = __builtin_amdgcn_mfma_f32_16x16x32_bf16(
                        afrag[m][ks], bfrag[nn][ks], acc[m][nn], 0, 0, 0);

        #pragma unroll
        for (int m = 0; m < 2; ++m) {
            const float4 xv = *(const float4*)&x_t[h][wave * 32 + m * 16 + lq * 4];
            #pragma unroll
            for (int nn = 0; nn < 2; ++nn) {
                macc[m][nn][0] += xv.x * acc[m][nn][0];
                macc[m][nn][1] += xv.y * acc[m][nn][1];
                macc[m][nn][2] += xv.z * acc[m][nn][2];
                macc[m][nn][3] += xv.w * acc[m][nn][3];
            }
        }
    }

    #pragma unroll
    for (int m = 0; m < 2; ++m) {
        int ebase = e0 + wave * 32 + m * 16 + lq * 4;
        const int4 p4 = *(const int4*)&pos[ebase];
        int pr[4] = { p4.x, p4.y, p4.z, p4.w };
        #pragma unroll
        for (int r = 0; r < 4; ++r) {
            if (ebase + r < E) {
                outp[(size_t)pr[r] * HH + lo]      = macc[m][0][r];
                outp[(size_t)pr[r] * HH + 16 + lo] = macc[m][1][r];
            }
        }
    }
}

// ---------------- ABLATION PROBE 1: staging + sync + ds_read, NO MFMA/epilogue ----------------
__global__ void __launch_bounds__(512, 2)
k_abl_nomfma(const unsigned short* __restrict__ Rb, const unsigned short* __restrict__ W2s,
             const float* __restrict__ b2, const float* __restrict__ cur,
             const int* __restrict__ src, int E) {
    __shared__ unsigned short w2buf[4][32 * EDGE_H];
    __shared__ float x_t[HH][M_TILE];
    __shared__ float b2_s[HH * HH];
    int t = threadIdx.x, wave = t >> 6, l = t & 63;
    int lo = l & 15, lq = l >> 4;
    int e0 = blockIdx.x * M_TILE;

    for (int i = t; i < HH * HH; i += 512) b2_s[i] = b2[i];
    for (int i = t; i < M_TILE * 8; i += 512) {
        int el = i >> 3, c = i & 7;
        int e = e0 + el;
        float4 v = make_float4(0.f, 0.f, 0.f, 0.f);
        if (e < E) v = ((const float4*)(cur + (size_t)src[e] * HH))[c];
        x_t[c * 4 + 0][el] = v.x; x_t[c * 4 + 1][el] = v.y;
        x_t[c * 4 + 2][el] = v.z; x_t[c * 4 + 3][el] = v.w;
    }
    bf16x8 afrag[2][4];
    #pragma unroll
    for (int m = 0; m < 2; ++m)
        #pragma unroll
        for (int ks = 0; ks < 4; ++ks) {
            afrag[m][ks] = *(const bf16x8*)(Rb + (size_t)(e0 + wave * 32 + m * 16 + lo) * EDGE_H + ks * 32 + lq * 8);
            asm volatile("" :: "v"(afrag[m][ks]));
        }
    #pragma unroll
    for (int s = 0; s < 3; ++s)
        gload_lds16(W2s + (size_t)s * 4096 + t * 8, &w2buf[s][t * 8]);
    asm volatile("s_waitcnt lgkmcnt(0)" ::: "memory");

    #pragma unroll 4
    for (int h = 0; h < HH; ++h) {
        if (h < 30)       asm volatile("s_waitcnt vmcnt(2)" ::: "memory");
        else if (h == 30) asm volatile("s_waitcnt vmcnt(1)" ::: "memory");
        else              asm volatile("s_waitcnt vmcnt(0)" ::: "memory");
        __builtin_amdgcn_s_barrier();
        if (h + 3 < HH)
            gload_lds16(W2s + (size_t)(h + 3) * 4096 + t * 8, &w2buf[(h + 3) & 3][t * 8]);

        const unsigned short* wb = w2buf[h & 3];
        #pragma unroll
        for (int nn = 0; nn < 2; ++nn)
            #pragma unroll
            for (int ks = 0; ks < 4; ++ks) {
                bf16x8 bf = *(const bf16x8*)&wb[(nn * 16 + lo) * EDGE_H + (((ks * 4 + lq) ^ lo) * 8)];
                asm volatile("" :: "v"(bf));
            }
        const float4 xv = *(const float4*)&x_t[h][wave * 32 + lq * 4];
        float bb = b2_s[h * HH + lo];
        asm volatile("" :: "v"(xv.x), "v"(xv.y), "v"(bb));
    }
}

// ---------------- ABLATION PROBE 2: + MFMA, NO epilogue/stores ----------------
__global__ void __launch_bounds__(512, 2)
k_abl_noepi(const unsigned short* __restrict__ Rb, const unsigned short* __restrict__ W2s,
            const float* __restrict__ b2, const float* __restrict__ cur,
            const int* __restrict__ src, int E) {
    __shared__ unsigned short w2buf[4][32 * EDGE_H];
    __shared__ float x_t[HH][M_TILE];
    __shared__ float b2_s[HH * HH];
    int t = threadIdx.x, wave = t >> 6, l = t & 63;
    int lo = l & 15, lq = l >> 4;
    int e0 = blockIdx.x * M_TILE;

    for (int i = t; i < HH * HH; i += 512) b2_s[i] = b2[i];
    for (int i = t; i < M_TILE * 8; i += 512) {
        int el = i >> 3, c = i & 7;
        int e = e0 + el;
        float4 v = make_float4(0.f, 0.f, 0.f, 0.f);
        if (e < E) v = ((const float4*)(cur + (size_t)src[e] * HH))[c];
        x_t[c * 4 + 0][el] = v.x; x_t[c * 4 + 1][el] = v.y;
        x_t[c * 4 + 2][el] = v.z; x_t[c * 4 + 3][el] = v.w;
    }
    bf16x8 afrag[2][4];
    #pragma unroll
    for (int m = 0; m < 2; ++m)
        #pragma unroll
        for (int ks = 0; ks < 4; ++ks)
            afrag[m][ks] = *(const bf16x8*)(Rb + (size_t)(e0 + wave * 32 + m * 16 + lo) * EDGE_H + ks * 32 + lq * 8);
    #pragma unroll
    for (int s = 0; s < 3; ++s)
        gload_lds16(W2s + (size_t)s * 4096 + t * 8, &w2buf[s][t * 8]);
    asm volatile("s_waitcnt lgkmcnt(0)" ::: "memory");

    #pragma unroll 4
    for (int h = 0; h < HH; ++h) {
        if (h < 30)       asm volatile("s_waitcnt vmcnt(2)" ::: "memory");
        else if (h == 30) asm volatile("s_waitcnt vmcnt(1)" ::: "memory");
        else              asm volatile("s_waitcnt vmcnt(0)" ::: "memory");
        __builtin_amdgcn_s_barrier();
        if (h + 3 < HH)
            gload_lds16(W2s + (size_t)(h + 3) * 4096 + t * 8, &w2buf[(h + 3) & 3][t * 8]);

        const unsigned short* wb = w2buf[h & 3];
        bf16x8 bfrag[2][4];
        #pragma unroll
        for (int nn = 0; nn < 2; ++nn)
            #pragma unroll
            for (int ks = 0; ks < 4; ++ks)
                bfrag[nn][ks] = *(const bf16x8*)&wb[(nn * 16 + lo) * EDGE_H + (((ks * 4 + lq) ^ lo) * 8)];

        f32x4 acc[2][2];
        #pragma unroll
        for (int nn = 0; nn < 2; ++nn) {
            float bb = b2_s[h * HH + nn * 16 + lo];
            acc[0][nn] = (f32x4){bb, bb, bb, bb};
            acc[1][nn] = (f32x4){bb, bb, bb, bb};
        }
        #pragma unroll
        for (int ks = 0; ks < 4; ++ks)
            #pragma unroll
            for (int m = 0; m < 2; ++m)
                #pragma unroll
                for (int nn = 0; nn < 2; ++nn)
                    acc[m][nn] = __builtin_amdgcn_mfma_f32_16x16x32_bf16(
                        afrag[m][ks], bfrag[nn][ks], acc[m][nn], 0, 0, 0);
        #pragma unroll
        for (int m = 0; m < 2; ++m)
            #pragma unroll
            for (int nn = 0; nn < 2; ++nn)
                asm volatile("" :: "v"(acc[m][nn]));
    }
}

// ---------------- node update: CSR gather-sum + conv/residual/lin1/relu (+opt BN stats) ----------------
__global__ void k_node_update(const float* __restrict__ msg_sorted, const int* __restrict__ offsets,
                              const float* __restrict__ cur, const float* __restrict__ h0,
                              const float* __restrict__ conv_bias,
                              const float* __restrict__ lin1_w, const float* __restrict__ lin1_b,
                              float* __restrict__ nxt, float* __restrict__ stats,
                              int do_stats, int n) {
    __shared__ float t_s[8][HH + 1];
    __shared__ float w_s[HH][HH + 1];
    __shared__ float s_s[8][HH + 1];
    __shared__ float q_s[8][HH + 1];
    int t = threadIdx.x;
    for (int i = t; i < HH * HH; i += 256) w_s[i >> 5][i & 31] = lin1_w[i];
    int nl = t >> 5, h = t & 31;
    int nn = blockIdx.x * 8 + nl;
    float tv = 0.f;
    if (nn < n) {
        int s0 = offsets[nn], s1 = offsets[nn + 1];
        float s = 0.f;
        for (int i = s0; i < s1; ++i) s += msg_sorted[(size_t)i * HH + h];
        size_t idx = (size_t)nn * HH + h;
        float conv = s + cur[idx] + conv_bias[h];
        tv = 0.5f * conv + 0.5f * h0[idx];
    }
    t_s[nl][h] = tv;
    __syncthreads();
    float v = 0.f;
    if (nn < n) {
        const float BETA = 1.0f / 3.0f;
        float d = lin1_b[h];
        #pragma unroll
        for (int k = 0; k < HH; ++k) d += t_s[nl][k] * w_s[h][k];
        v = fmaxf(BETA * d + (1.0f - BETA) * tv, 0.f);
        nxt[(size_t)nn * HH + h] = v;
    }
    if (do_stats) {
        s_s[nl][h] = v;
        q_s[nl][h] = v * v;
        __syncthreads();
        if (nl == 0) {
            float s = 0.f, q = 0.f;
            #pragma unroll
            for (int g = 0; g < 8; ++g) { s += s_s[g][h]; q += q_s[g][h]; }
            atomicAdd(&stats[h], s);
            atomicAdd(&stats[32 + h], q);
        }
    }
}

// ---------------- BN apply + y_sigmoid head ----------------
__global__ void k_node_out(const float* __restrict__ out, const float* __restrict__ stats,
                           const float* __restrict__ gamma, const float* __restrict__ beta,
                           const float* __restrict__ ylin_w, const float* __restrict__ ylin_b,
                           float* __restrict__ y_bn, float* __restrict__ y_sig, int n) {
    int nn = blockIdx.x * blockDim.x + threadIdx.x;
    if (nn >= n) return;
    float inv_n = 1.f / (float)n;
    float yb[HH];
    #pragma unroll
    for (int h = 0; h < HH; ++h) {
        float mu = stats[h] * inv_n;
        float var = stats[32 + h] * inv_n - mu * mu;
        float v = out[(size_t)nn * HH + h];
        yb[h] = (v - mu) * rsqrtf(var + 1e-5f) * gamma[h] + beta[h];
    }
    #pragma unroll
    for (int h = 0; h < HH; ++h) y_bn[(size_t)nn * HH + h] = yb[h];
    #pragma unroll
    for (int c = 0; c < 3; ++c) {
        float d = ylin_b[c];
        #pragma unroll
        for (int h = 0; h < HH; ++h) d += yb[h] * ylin_w[c * HH + h];
        y_sig[(size_t)nn * 3 + c] = 1.f / (1.f + expf(-d));
    }
}

// ---------------- edge-hop head ----------------
__global__ void k_edge_hop(const float* __restrict__ y_bn, const int* __restrict__ sl,
                           const int* __restrict__ dl, const float* __restrict__ w,
                           const float* __restrict__ b, float* __restrict__ outp, int e2) {
    int e = blockIdx.x * blockDim.x + threadIdx.x;
    if (e >= e2) return;
    const float4* a = (const float4*)(y_bn + (size_t)sl[e] * HH);
    const float4* c = (const float4*)(y_bn + (size_t)dl[e] * HH);
    float d = b[0];
    #pragma unroll
    for (int q = 0; q < 8; ++q) {
        float4 av = a[q], cv = c[q];
        float4 wv = ((const float4*)w)[q];
        d += av.x * cv.x * wv.x + av.y * cv.y * wv.y + av.z * cv.z * wv.z + av.w * cv.w * wv.w;
    }
    outp[e] = 1.f / (1.f + expf(-d));
}

extern "C" void kernel_launch(void* const* d_in, const int* in_sizes, int n_in,
                              void* d_out, int out_size, void* d_ws, size_t ws_size,
                              hipStream_t stream) {
    const float* n_feat   = (const float*)d_in[0];
    const float* e_feat   = (const float*)d_in[1];
    const int*   src      = (const int*)d_in[2];
    const int*   dst      = (const int*)d_in[3];
    const int*   src_list = (const int*)d_in[4];
    const int*   dst_list = (const int*)d_in[5];
    const float* lin0_w   = (const float*)d_in[6];
    const float* lin0_b   = (const float*)d_in[7];
    const float* en1_w    = (const float*)d_in[8];
    const float* en1_b    = (const float*)d_in[9];
    const float* en2_w    = (const float*)d_in[10];
    const float* en2_b    = (const float*)d_in[11];
    const float* conv_bias= (const float*)d_in[12];
    const float* lin1_w   = (const float*)d_in[13];
    const float* lin1_b   = (const float*)d_in[14];
    const float* bn_gamma = (const float*)d_in[15];
    const float* bn_beta  = (const float*)d_in[16];
    const float* ylin_w   = (const float*)d_in[17];
    const float* ylin_b   = (const float*)d_in[18];
    const float* ylin2_w  = (const float*)d_in[19];
    const float* ylin2_b  = (const float*)d_in[20];

    int n  = in_sizes[0] / NODE_IN;
    int E  = in_sizes[1] / EDGE_IN;
    int e2 = in_sizes[4];
    int E_pad = (E + M_TILE - 1) & ~(M_TILE - 1);

    float* ws    = (float*)d_ws;
    size_t nh    = (size_t)n * HH;
    float* out_a = ws;
    float* out_b = out_a + nh;
    float* h0    = out_b + nh;
    float* y_bn  = h0 + nh;
    float* stats = y_bn + nh;                               // 64 floats
    float* msg_sorted = stats + 64;                         // E_pad*32 f32
    unsigned short* W2s = (unsigned short*)(msg_sorted + (size_t)E_pad * HH);
    unsigned short* Rb  = W2s + 1024 * EDGE_H;              // E_pad*128 bf16
    int* ibase   = (int*)(Rb + (size_t)E_pad * EDGE_H);
    int* deg     = ibase;
    int* offtmp  = deg + n;
    int* bsum    = offtmp + n;
    int* offsets = bsum + 256;
    int* cursor  = offsets + n + 1;
    int* pos     = cursor + n;

    int nb = (n + 255) / 256;

    k_prep_w2<<<(1024 * EDGE_H) / 256, 256, 0, stream>>>(en2_w, W2s);
    k_prep_r<<<E_pad / 256, 256, 0, stream>>>(e_feat, en1_w, en1_b, Rb, E, E_pad);
    k_lin0<<<(n + 7) / 8, 256, 0, stream>>>(n_feat, lin0_w, lin0_b, out_a, h0, n);

    k_zero_int<<<nb, 256, 0, stream>>>(deg, n);
    k_hist<<<(E + 255) / 256, 256, 0, stream>>>(dst, deg, E);
    k_scan1<<<nb, 256, 0, stream>>>(deg, offtmp, bsum, n);
    k_scan2<<<1, 256, 0, stream>>>(bsum, nb);
    k_scan3<<<(n + 256) / 256, 256, 0, stream>>>(offtmp, bsum, offsets, cursor, n, E);
    k_scatter_pos<<<(E + 255) / 256, 256, 0, stream>>>(dst, offsets, cursor, pos, E);

    hipMemsetAsync(stats, 0, 64 * sizeof(float), stream);

    const float* cur = out_a;
    float* nxt = out_b;
    for (int s = 0; s < 3; ++s) {
        k_edge_mfma4<<<E_pad / M_TILE, 512, 0, stream>>>(
            Rb, W2s, en2_b, cur, src, pos, msg_sorted, E);
        k_node_update<<<(n + 7) / 8, 256, 0, stream>>>(
            msg_sorted, offsets, cur, h0, conv_bias, lin1_w, lin1_b, nxt,
            stats, (s == 2) ? 1 : 0, n);
        float* t = (float*)cur; cur = nxt; nxt = t;
    }

    float* y_sig = (float*)d_out;
    float* e_out = y_sig + (size_t)n * 3;
    k_node_out<<<(n + 255) / 256, 256, 0, stream>>>(
        cur, stats, bn_gamma, bn_beta, ylin_w, ylin_b, y_bn, y_sig, n);
    k_edge_hop<<<(e2 + 255) / 256, 256, 0, stream>>>(
        y_bn, src_list, dst_list, ylin2_w, ylin2_b, e_out, e2);

    // ---- ablation probes (no memory writes; asm keep-alives prevent DCE) ----
    k_abl_nomfma<<<E_pad / M_TILE, 512, 0, stream>>>(Rb, W2s, en2_b, cur, src, E);
    k_abl_noepi <<<E_pad / M_TILE, 512, 0, stream>>>(Rb, W2s, en2_b, cur, src, E);
}

// Round 15
// 318.387 us; speedup vs baseline: 1.4005x; 1.4005x over previous
//
#include <hip/hip_runtime.h>
#include <hip/hip_bf16.h>
#include <math.h>

#define HH 32
#define NODE_IN 64
#define EDGE_IN 16
#define EDGE_H 128
#define M_TILE 256   // edges per block in MFMA edge kernel (8 waves x 32 edges)

typedef __attribute__((ext_vector_type(8))) short bf16x8;
typedef __attribute__((ext_vector_type(4))) float f32x4;

__device__ inline unsigned short f2bf(float f) {
    union { float f; unsigned int u; } v; v.f = f;
    unsigned int r = v.u + 0x7fff + ((v.u >> 16) & 1);   // RNE (inputs never NaN)
    return (unsigned short)(r >> 16);
}

__device__ inline void gload_lds16(const void* g, void* lds) {
    __builtin_amdgcn_global_load_lds(
        (const __attribute__((address_space(1))) void*)g,
        (__attribute__((address_space(3))) void*)lds, 16, 0, 0);
}

// ---------------- prep: W2 f32 -> bf16, CHUNK-SWIZZLED global layout ----------------
__global__ void k_prep_w2(const float* __restrict__ en2_w, unsigned short* __restrict__ W2s) {
    int i = blockIdx.x * 256 + threadIdx.x;
    int r = i >> 7, q = i & 127;
    int p = q >> 3, sub = q & 7;
    int c = p ^ (r & 15);
    W2s[i] = f2bf(en2_w[r * EDGE_H + c * 8 + sub]);
}

// ---------------- prep: R = relu(e_feat @ en1_w^T + en1_b) -> bf16 [E_pad][128] ----------------
__global__ void __launch_bounds__(256, 4)
k_prep_r(const float* __restrict__ e_feat, const float* __restrict__ en1_w,
         const float* __restrict__ en1_b, unsigned short* __restrict__ Rb,
         int E, int E_pad) {
    int t = threadIdx.x, wave = t >> 6, l = t & 63;
    int lo = l & 15, lq = l >> 4;
    int ebase = blockIdx.x * 256 + wave * 64;

    bf16x8 bfrag[8];
    #pragma unroll
    for (int nt = 0; nt < 8; ++nt) {
        unsigned short br[8] = {0, 0, 0, 0, 0, 0, 0, 0};
        if (lq < 2) {
            const float* wr = en1_w + (nt * 16 + lo) * EDGE_IN + lq * 8;
            #pragma unroll
            for (int z = 0; z < 8; ++z) br[z] = f2bf(wr[z]);
        }
        bfrag[nt] = *(const bf16x8*)br;
    }
    float b1v[8];
    #pragma unroll
    for (int nt = 0; nt < 8; ++nt) b1v[nt] = en1_b[nt * 16 + lo];

    #pragma unroll
    for (int m = 0; m < 4; ++m) {
        int ea = ebase + m * 16 + lo;
        unsigned short ar[8] = {0, 0, 0, 0, 0, 0, 0, 0};
        if (lq < 2 && ea < E) {
            const float* er = e_feat + (size_t)ea * EDGE_IN + lq * 8;
            float4 v0 = ((const float4*)er)[0];
            float4 v1 = ((const float4*)er)[1];
            ar[0] = f2bf(v0.x); ar[1] = f2bf(v0.y); ar[2] = f2bf(v0.z); ar[3] = f2bf(v0.w);
            ar[4] = f2bf(v1.x); ar[5] = f2bf(v1.y); ar[6] = f2bf(v1.z); ar[7] = f2bf(v1.w);
        }
        bf16x8 af = *(const bf16x8*)ar;

        int erow = ebase + m * 16 + lq * 4;
        #pragma unroll
        for (int nt = 0; nt < 8; ++nt) {
            f32x4 acc = (f32x4){b1v[nt], b1v[nt], b1v[nt], b1v[nt]};
            acc = __builtin_amdgcn_mfma_f32_16x16x32_bf16(af, bfrag[nt], acc, 0, 0, 0);
            #pragma unroll
            for (int r = 0; r < 4; ++r)
                Rb[(size_t)(erow + r) * EDGE_H + nt * 16 + lo] = f2bf(fmaxf(acc[r], 0.f));
        }
    }
}

// ---------------- lin0 ----------------
__global__ void k_lin0(const float* __restrict__ nf, const float* __restrict__ w,
                       const float* __restrict__ b, float* __restrict__ out,
                       float* __restrict__ h0, int n) {
    __shared__ float nf_s[8][NODE_IN];
    __shared__ float w_s[HH][NODE_IN + 1];
    int t = threadIdx.x;
    for (int i = t; i < HH * NODE_IN; i += 256) w_s[i / NODE_IN][i % NODE_IN] = w[i];
    int n0 = blockIdx.x * 8;
    for (int i = t; i < 8 * NODE_IN; i += 256) {
        int nl = i / NODE_IN, k = i % NODE_IN;
        int nn = n0 + nl;
        nf_s[nl][k] = (nn < n) ? nf[(size_t)nn * NODE_IN + k] : 0.f;
    }
    __syncthreads();
    int nl = t >> 5, h = t & 31;
    int nn = n0 + nl;
    if (nn < n) {
        float acc = b[h];
        #pragma unroll
        for (int k = 0; k < NODE_IN; ++k) acc += nf_s[nl][k] * w_s[h][k];
        acc = fmaxf(acc, 0.f);
        out[(size_t)nn * HH + h] = acc;
        h0[(size_t)nn * HH + h] = acc;
    }
}

// ---------------- CSR build (by dst) ----------------
__global__ void k_zero_int(int* __restrict__ p, int n) {
    int i = blockIdx.x * 256 + threadIdx.x;
    if (i < n) p[i] = 0;
}
__global__ void k_hist(const int* __restrict__ dst, int* __restrict__ deg, int E) {
    int e = blockIdx.x * 256 + threadIdx.x;
    if (e < E) atomicAdd(&deg[dst[e]], 1);
}
__global__ void k_scan1(const int* __restrict__ deg, int* __restrict__ offtmp,
                        int* __restrict__ bsum, int n) {
    __shared__ int sh[256];
    int tid = threadIdx.x;
    int i = blockIdx.x * 256 + tid;
    int v = (i < n) ? deg[i] : 0;
    sh[tid] = v;
    __syncthreads();
    for (int d = 1; d < 256; d <<= 1) {
        int add = (tid >= d) ? sh[tid - d] : 0;
        __syncthreads();
        sh[tid] += add;
        __syncthreads();
    }
    if (i < n) offtmp[i] = sh[tid] - v;
    if (tid == 255) bsum[blockIdx.x] = sh[255];
}
__global__ void k_scan2(int* __restrict__ bsum, int nb) {
    __shared__ int sh[256];
    int tid = threadIdx.x;
    int v = (tid < nb) ? bsum[tid] : 0;
    sh[tid] = v;
    __syncthreads();
    for (int d = 1; d < 256; d <<= 1) {
        int add = (tid >= d) ? sh[tid - d] : 0;
        __syncthreads();
        sh[tid] += add;
        __syncthreads();
    }
    if (tid < nb) bsum[tid] = sh[tid] - v;
}
__global__ void k_scan3(const int* __restrict__ offtmp, const int* __restrict__ bsum,
                        int* __restrict__ offsets, int* __restrict__ cursor, int n, int E) {
    int i = blockIdx.x * 256 + threadIdx.x;
    if (i < n) { offsets[i] = offtmp[i] + bsum[i >> 8]; cursor[i] = 0; }
    if (i == n) offsets[n] = E;
}
__global__ void k_scatter_pos(const int* __restrict__ dst, const int* __restrict__ offsets,
                              int* __restrict__ cursor, int* __restrict__ pos, int E) {
    int e = blockIdx.x * 256 + threadIdx.x;
    if (e < E) pos[e] = offsets[dst[e]] + atomicAdd(&cursor[dst[e]], 1);
}

// ---------------- MFMA edge kernel v4 (proven best: 51us) ----------------
__global__ void __launch_bounds__(512, 2)
k_edge_mfma4(const unsigned short* __restrict__ Rb, const unsigned short* __restrict__ W2s,
             const float* __restrict__ b2, const float* __restrict__ cur,
             const int* __restrict__ src, const int* __restrict__ pos,
             float* __restrict__ outp, int E) {
    __shared__ unsigned short w2buf[4][32 * EDGE_H];
    __shared__ float x_t[HH][M_TILE];
    __shared__ float b2_s[HH * HH];
    int t = threadIdx.x, wave = t >> 6, l = t & 63;
    int lo = l & 15, lq = l >> 4;
    int e0 = blockIdx.x * M_TILE;

    for (int i = t; i < HH * HH; i += 512) b2_s[i] = b2[i];

    for (int i = t; i < M_TILE * 8; i += 512) {
        int el = i >> 3, c = i & 7;
        int e = e0 + el;
        float4 v = make_float4(0.f, 0.f, 0.f, 0.f);
        if (e < E) v = ((const float4*)(cur + (size_t)src[e] * HH))[c];
        x_t[c * 4 + 0][el] = v.x; x_t[c * 4 + 1][el] = v.y;
        x_t[c * 4 + 2][el] = v.z; x_t[c * 4 + 3][el] = v.w;
    }

    bf16x8 afrag[2][4];
    #pragma unroll
    for (int m = 0; m < 2; ++m)
        #pragma unroll
        for (int ks = 0; ks < 4; ++ks)
            afrag[m][ks] = *(const bf16x8*)(Rb + (size_t)(e0 + wave * 32 + m * 16 + lo) * EDGE_H + ks * 32 + lq * 8);

    #pragma unroll
    for (int s = 0; s < 3; ++s)
        gload_lds16(W2s + (size_t)s * 4096 + t * 8, &w2buf[s][t * 8]);

    asm volatile("s_waitcnt lgkmcnt(0)" ::: "memory");

    float macc[2][2][4];
    #pragma unroll
    for (int m = 0; m < 2; ++m)
        #pragma unroll
        for (int nn = 0; nn < 2; ++nn)
            #pragma unroll
            for (int r = 0; r < 4; ++r) macc[m][nn][r] = 0.f;

    #pragma unroll 4
    for (int h = 0; h < HH; ++h) {
        if (h < 30)       asm volatile("s_waitcnt vmcnt(2)" ::: "memory");
        else if (h == 30) asm volatile("s_waitcnt vmcnt(1)" ::: "memory");
        else              asm volatile("s_waitcnt vmcnt(0)" ::: "memory");
        __builtin_amdgcn_s_barrier();
        if (h + 3 < HH)
            gload_lds16(W2s + (size_t)(h + 3) * 4096 + t * 8, &w2buf[(h + 3) & 3][t * 8]);

        const unsigned short* wb = w2buf[h & 3];
        bf16x8 bfrag[2][4];
        #pragma unroll
        for (int nn = 0; nn < 2; ++nn)
            #pragma unroll
            for (int ks = 0; ks < 4; ++ks)
                bfrag[nn][ks] = *(const bf16x8*)&wb[(nn * 16 + lo) * EDGE_H + (((ks * 4 + lq) ^ lo) * 8)];

        f32x4 acc[2][2];
        #pragma unroll
        for (int nn = 0; nn < 2; ++nn) {
            float bb = b2_s[h * HH + nn * 16 + lo];
            acc[0][nn] = (f32x4){bb, bb, bb, bb};
            acc[1][nn] = (f32x4){bb, bb, bb, bb};
        }
        #pragma unroll
        for (int ks = 0; ks < 4; ++ks)
            #pragma unroll
            for (int m = 0; m < 2; ++m)
                #pragma unroll
                for (int nn = 0; nn < 2; ++nn)
                    acc[m][nn] = __builtin_amdgcn_mfma_f32_16x16x32_bf16(
                        afrag[m][ks], bfrag[nn][ks], acc[m][nn], 0, 0, 0);

        #pragma unroll
        for (int m = 0; m < 2; ++m) {
            const float4 xv = *(const float4*)&x_t[h][wave * 32 + m * 16 + lq * 4];
            #pragma unroll
            for (int nn = 0; nn < 2; ++nn) {
                macc[m][nn][0] += xv.x * acc[m][nn][0];
                macc[m][nn][1] += xv.y * acc[m][nn][1];
                macc[m][nn][2] += xv.z * acc[m][nn][2];
                macc[m][nn][3] += xv.w * acc[m][nn][3];
            }
        }
    }

    #pragma unroll
    for (int m = 0; m < 2; ++m) {
        int ebase = e0 + wave * 32 + m * 16 + lq * 4;
        const int4 p4 = *(const int4*)&pos[ebase];
        int pr[4] = { p4.x, p4.y, p4.z, p4.w };
        #pragma unroll
        for (int r = 0; r < 4; ++r) {
            if (ebase + r < E) {
                outp[(size_t)pr[r] * HH + lo]      = macc[m][0][r];
                outp[(size_t)pr[r] * HH + 16 + lo] = macc[m][1][r];
            }
        }
    }
}

// ---------------- ABLATION PROBE 1: staging + sync + ds_read, NO MFMA/epilogue ----------------
__global__ void __launch_bounds__(512, 2)
k_abl_nomfma(const unsigned short* __restrict__ Rb, const unsigned short* __restrict__ W2s,
             const float* __restrict__ b2, const float* __restrict__ cur,
             const int* __restrict__ src, int E) {
    __shared__ unsigned short w2buf[4][32 * EDGE_H];
    __shared__ float x_t[HH][M_TILE];
    __shared__ float b2_s[HH * HH];
    int t = threadIdx.x, wave = t >> 6, l = t & 63;
    int lo = l & 15, lq = l >> 4;
    int e0 = blockIdx.x * M_TILE;

    for (int i = t; i < HH * HH; i += 512) b2_s[i] = b2[i];
    for (int i = t; i < M_TILE * 8; i += 512) {
        int el = i >> 3, c = i & 7;
        int e = e0 + el;
        float4 v = make_float4(0.f, 0.f, 0.f, 0.f);
        if (e < E) v = ((const float4*)(cur + (size_t)src[e] * HH))[c];
        x_t[c * 4 + 0][el] = v.x; x_t[c * 4 + 1][el] = v.y;
        x_t[c * 4 + 2][el] = v.z; x_t[c * 4 + 3][el] = v.w;
    }
    bf16x8 afrag[2][4];
    #pragma unroll
    for (int m = 0; m < 2; ++m)
        #pragma unroll
        for (int ks = 0; ks < 4; ++ks) {
            afrag[m][ks] = *(const bf16x8*)(Rb + (size_t)(e0 + wave * 32 + m * 16 + lo) * EDGE_H + ks * 32 + lq * 8);
            asm volatile("" :: "v"(afrag[m][ks]));
        }
    #pragma unroll
    for (int s = 0; s < 3; ++s)
        gload_lds16(W2s + (size_t)s * 4096 + t * 8, &w2buf[s][t * 8]);
    asm volatile("s_waitcnt lgkmcnt(0)" ::: "memory");

    #pragma unroll 4
    for (int h = 0; h < HH; ++h) {
        if (h < 30)       asm volatile("s_waitcnt vmcnt(2)" ::: "memory");
        else if (h == 30) asm volatile("s_waitcnt vmcnt(1)" ::: "memory");
        else              asm volatile("s_waitcnt vmcnt(0)" ::: "memory");
        __builtin_amdgcn_s_barrier();
        if (h + 3 < HH)
            gload_lds16(W2s + (size_t)(h + 3) * 4096 + t * 8, &w2buf[(h + 3) & 3][t * 8]);

        const unsigned short* wb = w2buf[h & 3];
        #pragma unroll
        for (int nn = 0; nn < 2; ++nn)
            #pragma unroll
            for (int ks = 0; ks < 4; ++ks) {
                bf16x8 bf = *(const bf16x8*)&wb[(nn * 16 + lo) * EDGE_H + (((ks * 4 + lq) ^ lo) * 8)];
                asm volatile("" :: "v"(bf));
            }
        const float4 xv = *(const float4*)&x_t[h][wave * 32 + lq * 4];
        float bb = b2_s[h * HH + lo];
        asm volatile("" :: "v"(xv.x), "v"(xv.y), "v"(bb));
    }
}

// ---------------- ABLATION PROBE 2: + MFMA, NO epilogue/stores ----------------
__global__ void __launch_bounds__(512, 2)
k_abl_noepi(const unsigned short* __restrict__ Rb, const unsigned short* __restrict__ W2s,
            const float* __restrict__ b2, const float* __restrict__ cur,
            const int* __restrict__ src, int E) {
    __shared__ unsigned short w2buf[4][32 * EDGE_H];
    __shared__ float x_t[HH][M_TILE];
    __shared__ float b2_s[HH * HH];
    int t = threadIdx.x, wave = t >> 6, l = t & 63;
    int lo = l & 15, lq = l >> 4;
    int e0 = blockIdx.x * M_TILE;

    for (int i = t; i < HH * HH; i += 512) b2_s[i] = b2[i];
    for (int i = t; i < M_TILE * 8; i += 512) {
        int el = i >> 3, c = i & 7;
        int e = e0 + el;
        float4 v = make_float4(0.f, 0.f, 0.f, 0.f);
        if (e < E) v = ((const float4*)(cur + (size_t)src[e] * HH))[c];
        x_t[c * 4 + 0][el] = v.x; x_t[c * 4 + 1][el] = v.y;
        x_t[c * 4 + 2][el] = v.z; x_t[c * 4 + 3][el] = v.w;
    }
    bf16x8 afrag[2][4];
    #pragma unroll
    for (int m = 0; m < 2; ++m)
        #pragma unroll
        for (int ks = 0; ks < 4; ++ks)
            afrag[m][ks] = *(const bf16x8*)(Rb + (size_t)(e0 + wave * 32 + m * 16 + lo) * EDGE_H + ks * 32 + lq * 8);
    #pragma unroll
    for (int s = 0; s < 3; ++s)
        gload_lds16(W2s + (size_t)s * 4096 + t * 8, &w2buf[s][t * 8]);
    asm volatile("s_waitcnt lgkmcnt(0)" ::: "memory");

    #pragma unroll 4
    for (int h = 0; h < HH; ++h) {
        if (h < 30)       asm volatile("s_waitcnt vmcnt(2)" ::: "memory");
        else if (h == 30) asm volatile("s_waitcnt vmcnt(1)" ::: "memory");
        else              asm volatile("s_waitcnt vmcnt(0)" ::: "memory");
        __builtin_amdgcn_s_barrier();
        if (h + 3 < HH)
            gload_lds16(W2s + (size_t)(h + 3) * 4096 + t * 8, &w2buf[(h + 3) & 3][t * 8]);

        const unsigned short* wb = w2buf[h & 3];
        bf16x8 bfrag[2][4];
        #pragma unroll
        for (int nn = 0; nn < 2; ++nn)
            #pragma unroll
            for (int ks = 0; ks < 4; ++ks)
                bfrag[nn][ks] = *(const bf16x8*)&wb[(nn * 16 + lo) * EDGE_H + (((ks * 4 + lq) ^ lo) * 8)];

        f32x4 acc[2][2];
        #pragma unroll
        for (int nn = 0; nn < 2; ++nn) {
            float bb = b2_s[h * HH + nn * 16 + lo];
            acc[0][nn] = (f32x4){bb, bb, bb, bb};
            acc[1][nn] = (f32x4){bb, bb, bb, bb};
        }
        #pragma unroll
        for (int ks = 0; ks < 4; ++ks)
            #pragma unroll
            for (int m = 0; m < 2; ++m)
                #pragma unroll
                for (int nn = 0; nn < 2; ++nn)
                    acc[m][nn] = __builtin_amdgcn_mfma_f32_16x16x32_bf16(
                        afrag[m][ks], bfrag[nn][ks], acc[m][nn], 0, 0, 0);
        #pragma unroll
        for (int m = 0; m < 2; ++m)
            #pragma unroll
            for (int nn = 0; nn < 2; ++nn)
                asm volatile("" :: "v"(acc[m][nn]));
    }
}

// ---------------- node update: CSR gather-sum + conv/residual/lin1/relu (R7-exact) ----------------
__global__ void k_node_update(const float* __restrict__ msg_sorted, const int* __restrict__ offsets,
                              const float* __restrict__ cur, const float* __restrict__ h0,
                              const float* __restrict__ conv_bias,
                              const float* __restrict__ lin1_w, const float* __restrict__ lin1_b,
                              float* __restrict__ nxt, int n) {
    __shared__ float t_s[8][HH + 1];
    __shared__ float w_s[HH][HH + 1];
    int t = threadIdx.x;
    for (int i = t; i < HH * HH; i += 256) w_s[i >> 5][i & 31] = lin1_w[i];
    int nl = t >> 5, h = t & 31;
    int nn = blockIdx.x * 8 + nl;
    float tv = 0.f;
    if (nn < n) {
        int s0 = offsets[nn], s1 = offsets[nn + 1];
        float s = 0.f;
        for (int i = s0; i < s1; ++i) s += msg_sorted[(size_t)i * HH + h];
        size_t idx = (size_t)nn * HH + h;
        float conv = s + cur[idx] + conv_bias[h];
        tv = 0.5f * conv + 0.5f * h0[idx];
    }
    t_s[nl][h] = tv;
    __syncthreads();
    if (nn < n) {
        const float BETA = 1.0f / 3.0f;
        float d = lin1_b[h];
        #pragma unroll
        for (int k = 0; k < HH; ++k) d += t_s[nl][k] * w_s[h][k];
        float v = BETA * d + (1.0f - BETA) * tv;
        nxt[(size_t)nn * HH + h] = fmaxf(v, 0.f);
    }
}

// ---------------- BN batch statistics (R7-exact, separate) ----------------
__global__ void k_bn_stats(const float* __restrict__ out, float* __restrict__ stats, int n) {
    int t = threadIdx.x;
    int h = t & 31, rg = t >> 5;
    float s = 0.f, s2 = 0.f;
    for (int nn = blockIdx.x * 8 + rg; nn < n; nn += gridDim.x * 8) {
        float v = out[(size_t)nn * HH + h];
        s += v; s2 += v * v;
    }
    __shared__ float sh[256], sh2[256];
    sh[t] = s; sh2[t] = s2;
    __syncthreads();
    if (rg == 0) {
        #pragma unroll
        for (int g = 1; g < 8; ++g) { s += sh[g * 32 + h]; s2 += sh2[g * 32 + h]; }
        atomicAdd(&stats[h], s);
        atomicAdd(&stats[32 + h], s2);
    }
}

// ---------------- BN apply + y_sigmoid head ----------------
__global__ void k_node_out(const float* __restrict__ out, const float* __restrict__ stats,
                           const float* __restrict__ gamma, const float* __restrict__ beta,
                           const float* __restrict__ ylin_w, const float* __restrict__ ylin_b,
                           float* __restrict__ y_bn, float* __restrict__ y_sig, int n) {
    int nn = blockIdx.x * blockDim.x + threadIdx.x;
    if (nn >= n) return;
    float inv_n = 1.f / (float)n;
    float yb[HH];
    #pragma unroll
    for (int h = 0; h < HH; ++h) {
        float mu = stats[h] * inv_n;
        float var = stats[32 + h] * inv_n - mu * mu;
        float v = out[(size_t)nn * HH + h];
        yb[h] = (v - mu) * rsqrtf(var + 1e-5f) * gamma[h] + beta[h];
    }
    #pragma unroll
    for (int h = 0; h < HH; ++h) y_bn[(size_t)nn * HH + h] = yb[h];
    #pragma unroll
    for (int c = 0; c < 3; ++c) {
        float d = ylin_b[c];
        #pragma unroll
        for (int h = 0; h < HH; ++h) d += yb[h] * ylin_w[c * HH + h];
        y_sig[(size_t)nn * 3 + c] = 1.f / (1.f + expf(-d));
    }
}

// ---------------- edge-hop head ----------------
__global__ void k_edge_hop(const float* __restrict__ y_bn, const int* __restrict__ sl,
                           const int* __restrict__ dl, const float* __restrict__ w,
                           const float* __restrict__ b, float* __restrict__ outp, int e2) {
    int e = blockIdx.x * blockDim.x + threadIdx.x;
    if (e >= e2) return;
    const float4* a = (const float4*)(y_bn + (size_t)sl[e] * HH);
    const float4* c = (const float4*)(y_bn + (size_t)dl[e] * HH);
    float d = b[0];
    #pragma unroll
    for (int q = 0; q < 8; ++q) {
        float4 av = a[q], cv = c[q];
        float4 wv = ((const float4*)w)[q];
        d += av.x * cv.x * wv.x + av.y * cv.y * wv.y + av.z * cv.z * wv.z + av.w * cv.w * wv.w;
    }
    outp[e] = 1.f / (1.f + expf(-d));
}

extern "C" void kernel_launch(void* const* d_in, const int* in_sizes, int n_in,
                              void* d_out, int out_size, void* d_ws, size_t ws_size,
                              hipStream_t stream) {
    const float* n_feat   = (const float*)d_in[0];
    const float* e_feat   = (const float*)d_in[1];
    const int*   src      = (const int*)d_in[2];
    const int*   dst      = (const int*)d_in[3];
    const int*   src_list = (const int*)d_in[4];
    const int*   dst_list = (const int*)d_in[5];
    const float* lin0_w   = (const float*)d_in[6];
    const float* lin0_b   = (const float*)d_in[7];
    const float* en1_w    = (const float*)d_in[8];
    const float* en1_b    = (const float*)d_in[9];
    const float* en2_w    = (const float*)d_in[10];
    const float* en2_b    = (const float*)d_in[11];
    const float* conv_bias= (const float*)d_in[12];
    const float* lin1_w   = (const float*)d_in[13];
    const float* lin1_b   = (const float*)d_in[14];
    const float* bn_gamma = (const float*)d_in[15];
    const float* bn_beta  = (const float*)d_in[16];
    const float* ylin_w   = (const float*)d_in[17];
    const float* ylin_b   = (const float*)d_in[18];
    const float* ylin2_w  = (const float*)d_in[19];
    const float* ylin2_b  = (const float*)d_in[20];

    int n  = in_sizes[0] / NODE_IN;
    int E  = in_sizes[1] / EDGE_IN;
    int e2 = in_sizes[4];
    int E_pad = (E + M_TILE - 1) & ~(M_TILE - 1);

    float* ws    = (float*)d_ws;
    size_t nh    = (size_t)n * HH;
    float* out_a = ws;
    float* out_b = out_a + nh;
    float* h0    = out_b + nh;
    float* y_bn  = h0 + nh;
    float* stats = y_bn + nh;                               // 64 floats
    float* msg_sorted = stats + 64;                         // E_pad*32 f32
    unsigned short* W2s = (unsigned short*)(msg_sorted + (size_t)E_pad * HH);
    unsigned short* Rb  = W2s + 1024 * EDGE_H;              // E_pad*128 bf16
    int* ibase   = (int*)(Rb + (size_t)E_pad * EDGE_H);
    int* deg     = ibase;
    int* offtmp  = deg + n;
    int* bsum    = offtmp + n;
    int* offsets = bsum + 256;
    int* cursor  = offsets + n + 1;
    int* pos     = cursor + n;

    int nb = (n + 255) / 256;

    k_prep_w2<<<(1024 * EDGE_H) / 256, 256, 0, stream>>>(en2_w, W2s);
    k_prep_r<<<E_pad / 256, 256, 0, stream>>>(e_feat, en1_w, en1_b, Rb, E, E_pad);
    k_lin0<<<(n + 7) / 8, 256, 0, stream>>>(n_feat, lin0_w, lin0_b, out_a, h0, n);

    k_zero_int<<<nb, 256, 0, stream>>>(deg, n);
    k_hist<<<(E + 255) / 256, 256, 0, stream>>>(dst, deg, E);
    k_scan1<<<nb, 256, 0, stream>>>(deg, offtmp, bsum, n);
    k_scan2<<<1, 256, 0, stream>>>(bsum, nb);
    k_scan3<<<(n + 256) / 256, 256, 0, stream>>>(offtmp, bsum, offsets, cursor, n, E);
    k_scatter_pos<<<(E + 255) / 256, 256, 0, stream>>>(dst, offsets, cursor, pos, E);

    const float* cur = out_a;
    float* nxt = out_b;
    for (int s = 0; s < 3; ++s) {
        k_edge_mfma4<<<E_pad / M_TILE, 512, 0, stream>>>(
            Rb, W2s, en2_b, cur, src, pos, msg_sorted, E);
        k_node_update<<<(n + 7) / 8, 256, 0, stream>>>(
            msg_sorted, offsets, cur, h0, conv_bias, lin1_w, lin1_b, nxt, n);
        float* t = (float*)cur; cur = nxt; nxt = t;
    }

    hipMemsetAsync(stats, 0, 64 * sizeof(float), stream);
    k_bn_stats<<<256, 256, 0, stream>>>(cur, stats, n);

    float* y_sig = (float*)d_out;
    float* e_out = y_sig + (size_t)n * 3;
    k_node_out<<<(n + 255) / 256, 256, 0, stream>>>(
        cur, stats, bn_gamma, bn_beta, ylin_w, ylin_b, y_bn, y_sig, n);
    k_edge_hop<<<(e2 + 255) / 256, 256, 0, stream>>>(
        y_bn, src_list, dst_list, ylin2_w, ylin2_b, e_out, e2);

    // ---- ablation probes (no memory writes; asm keep-alives prevent DCE) ----
    k_abl_nomfma<<<E_pad / M_TILE, 512, 0, stream>>>(Rb, W2s, en2_b, cur, src, E);
    k_abl_noepi <<<E_pad / M_TILE, 512, 0, stream>>>(Rb, W2s, en2_b, cur, src, E);
}

// Round 16
// 302.160 us; speedup vs baseline: 1.4757x; 1.0537x over previous
//
#include <hip/hip_runtime.h>
#include <hip/hip_bf16.h>
#include <math.h>

#define HH 32
#define NODE_IN 64
#define EDGE_IN 16
#define EDGE_H 128
#define ET8 64        // edges per tile in edge kernel v8
#define E_PAD_UNIT 256

typedef __attribute__((ext_vector_type(8))) short bf16x8;
typedef __attribute__((ext_vector_type(4))) float f32x4;

__device__ inline unsigned short f2bf(float f) {
    union { float f; unsigned int u; } v; v.f = f;
    unsigned int r = v.u + 0x7fff + ((v.u >> 16) & 1);   // RNE (inputs never NaN)
    return (unsigned short)(r >> 16);
}

// ---------------- prep: W2 f32 -> bf16 (LINEAR layout; B consumed from registers now) ----------------
__global__ void k_prep_w2(const float* __restrict__ en2_w, unsigned short* __restrict__ W2b) {
    int i = blockIdx.x * 256 + threadIdx.x;
    W2b[i] = f2bf(en2_w[i]);
}

// ---------------- prep: R = relu(e_feat @ en1_w^T + en1_b) -> bf16 [E_pad][128] ----------------
__global__ void __launch_bounds__(256, 4)
k_prep_r(const float* __restrict__ e_feat, const float* __restrict__ en1_w,
         const float* __restrict__ en1_b, unsigned short* __restrict__ Rb,
         int E, int E_pad) {
    int t = threadIdx.x, wave = t >> 6, l = t & 63;
    int lo = l & 15, lq = l >> 4;
    int ebase = blockIdx.x * 256 + wave * 64;

    bf16x8 bfrag[8];
    #pragma unroll
    for (int nt = 0; nt < 8; ++nt) {
        unsigned short br[8] = {0, 0, 0, 0, 0, 0, 0, 0};
        if (lq < 2) {
            const float* wr = en1_w + (nt * 16 + lo) * EDGE_IN + lq * 8;
            #pragma unroll
            for (int z = 0; z < 8; ++z) br[z] = f2bf(wr[z]);
        }
        bfrag[nt] = *(const bf16x8*)br;
    }
    float b1v[8];
    #pragma unroll
    for (int nt = 0; nt < 8; ++nt) b1v[nt] = en1_b[nt * 16 + lo];

    #pragma unroll
    for (int m = 0; m < 4; ++m) {
        int ea = ebase + m * 16 + lo;
        unsigned short ar[8] = {0, 0, 0, 0, 0, 0, 0, 0};
        if (lq < 2 && ea < E) {
            const float* er = e_feat + (size_t)ea * EDGE_IN + lq * 8;
            float4 v0 = ((const float4*)er)[0];
            float4 v1 = ((const float4*)er)[1];
            ar[0] = f2bf(v0.x); ar[1] = f2bf(v0.y); ar[2] = f2bf(v0.z); ar[3] = f2bf(v0.w);
            ar[4] = f2bf(v1.x); ar[5] = f2bf(v1.y); ar[6] = f2bf(v1.z); ar[7] = f2bf(v1.w);
        }
        bf16x8 af = *(const bf16x8*)ar;

        int erow = ebase + m * 16 + lq * 4;
        #pragma unroll
        for (int nt = 0; nt < 8; ++nt) {
            f32x4 acc = (f32x4){b1v[nt], b1v[nt], b1v[nt], b1v[nt]};
            acc = __builtin_amdgcn_mfma_f32_16x16x32_bf16(af, bfrag[nt], acc, 0, 0, 0);
            #pragma unroll
            for (int r = 0; r < 4; ++r)
                Rb[(size_t)(erow + r) * EDGE_H + nt * 16 + lo] = f2bf(fmaxf(acc[r], 0.f));
        }
    }
}

// ---------------- lin0 ----------------
__global__ void k_lin0(const float* __restrict__ nf, const float* __restrict__ w,
                       const float* __restrict__ b, float* __restrict__ out,
                       float* __restrict__ h0, int n) {
    __shared__ float nf_s[8][NODE_IN];
    __shared__ float w_s[HH][NODE_IN + 1];
    int t = threadIdx.x;
    for (int i = t; i < HH * NODE_IN; i += 256) w_s[i / NODE_IN][i % NODE_IN] = w[i];
    int n0 = blockIdx.x * 8;
    for (int i = t; i < 8 * NODE_IN; i += 256) {
        int nl = i / NODE_IN, k = i % NODE_IN;
        int nn = n0 + nl;
        nf_s[nl][k] = (nn < n) ? nf[(size_t)nn * NODE_IN + k] : 0.f;
    }
    __syncthreads();
    int nl = t >> 5, h = t & 31;
    int nn = n0 + nl;
    if (nn < n) {
        float acc = b[h];
        #pragma unroll
        for (int k = 0; k < NODE_IN; ++k) acc += nf_s[nl][k] * w_s[h][k];
        acc = fmaxf(acc, 0.f);
        out[(size_t)nn * HH + h] = acc;
        h0[(size_t)nn * HH + h] = acc;
    }
}

// ---------------- CSR build (by dst) ----------------
__global__ void k_zero_int(int* __restrict__ p, int n) {
    int i = blockIdx.x * 256 + threadIdx.x;
    if (i < n) p[i] = 0;
}
__global__ void k_hist(const int* __restrict__ dst, int* __restrict__ deg, int E) {
    int e = blockIdx.x * 256 + threadIdx.x;
    if (e < E) atomicAdd(&deg[dst[e]], 1);
}
__global__ void k_scan1(const int* __restrict__ deg, int* __restrict__ offtmp,
                        int* __restrict__ bsum, int n) {
    __shared__ int sh[256];
    int tid = threadIdx.x;
    int i = blockIdx.x * 256 + tid;
    int v = (i < n) ? deg[i] : 0;
    sh[tid] = v;
    __syncthreads();
    for (int d = 1; d < 256; d <<= 1) {
        int add = (tid >= d) ? sh[tid - d] : 0;
        __syncthreads();
        sh[tid] += add;
        __syncthreads();
    }
    if (i < n) offtmp[i] = sh[tid] - v;
    if (tid == 255) bsum[blockIdx.x] = sh[255];
}
__global__ void k_scan2(int* __restrict__ bsum, int nb) {
    __shared__ int sh[256];
    int tid = threadIdx.x;
    int v = (tid < nb) ? bsum[tid] : 0;
    sh[tid] = v;
    __syncthreads();
    for (int d = 1; d < 256; d <<= 1) {
        int add = (tid >= d) ? sh[tid - d] : 0;
        __syncthreads();
        sh[tid] += add;
        __syncthreads();
    }
    if (tid < nb) bsum[tid] = sh[tid] - v;
}
__global__ void k_scan3(const int* __restrict__ offtmp, const int* __restrict__ bsum,
                        int* __restrict__ offsets, int* __restrict__ cursor, int n, int E) {
    int i = blockIdx.x * 256 + threadIdx.x;
    if (i < n) { offsets[i] = offtmp[i] + bsum[i >> 8]; cursor[i] = 0; }
    if (i == n) offsets[n] = E;
}
__global__ void k_scatter_pos(const int* __restrict__ dst, const int* __restrict__ offsets,
                              int* __restrict__ cursor, int* __restrict__ pos, int E) {
    int e = blockIdx.x * 256 + threadIdx.x;
    if (e < E) pos[e] = offsets[dst[e]] + atomicAdd(&cursor[dst[e]], 1);
}

// ---------------- MFMA edge kernel v8: W2 register-resident, zero LDS in MFMA loop ----------------
// 256 blocks x 8 waves (2/SIMD). Each wave holds 4 h-slices of W2 in VGPRs
// (bfrag[4][2][4] = 128 VGPR), loaded ONCE. Loop over 64-edge tiles:
// A from L1/L2 into regs, 128 MFMA/wave vs register operands, x_t double-buffered,
// cross-wave h-reduce through 4 LDS slots, CSR store via pos.
__global__ void __launch_bounds__(512, 2)
k_edge_mfma8(const unsigned short* __restrict__ Rb, const unsigned short* __restrict__ W2b,
             const float* __restrict__ b2, const float* __restrict__ cur,
             const int* __restrict__ src, const int* __restrict__ pos,
             float* __restrict__ outp, int E, int tiles) {
    __shared__ float x_t[2][HH][ET8 + 4];   // 17.4 KB (double-buffered, [h][edge])
    __shared__ float slots[4][ET8 * 33];    // 33.8 KB cross-wave reduce
    int t = threadIdx.x, wave = t >> 6, l = t & 63;
    int lo = l & 15, lq = l >> 4;

    // persistent B: wave owns h = wave*4 + hh
    bf16x8 bfrag[4][2][4];
    float b2v[4][2];
    #pragma unroll
    for (int hh = 0; hh < 4; ++hh) {
        int h = wave * 4 + hh;
        #pragma unroll
        for (int nn = 0; nn < 2; ++nn) {
            b2v[hh][nn] = b2[h * HH + nn * 16 + lo];
            #pragma unroll
            for (int ks = 0; ks < 4; ++ks)
                bfrag[hh][nn][ks] = *(const bf16x8*)(W2b + (size_t)(h * HH + nn * 16 + lo) * EDGE_H + ks * 32 + lq * 8);
        }
    }

    // stage x for first tile into buffer 0
    {
        int e0 = blockIdx.x * ET8;
        for (int i = t; i < ET8 * 8; i += 512) {
            int el = i >> 3, c = i & 7;
            int e = e0 + el;
            float4 v = make_float4(0.f, 0.f, 0.f, 0.f);
            if (e < E) v = ((const float4*)(cur + (size_t)src[e] * HH))[c];
            x_t[0][c * 4 + 0][el] = v.x; x_t[0][c * 4 + 1][el] = v.y;
            x_t[0][c * 4 + 2][el] = v.z; x_t[0][c * 4 + 3][el] = v.w;
        }
    }
    __syncthreads();

    int it = 0;
    for (int tile = blockIdx.x; tile < tiles; tile += gridDim.x, ++it) {
        int cb = it & 1;
        int e0 = tile * ET8;

        // stage x for NEXT tile into the other buffer (overlaps with compute)
        int ntile = tile + gridDim.x;
        if (ntile < tiles) {
            int ne0 = ntile * ET8;
            for (int i = t; i < ET8 * 8; i += 512) {
                int el = i >> 3, c = i & 7;
                int e = ne0 + el;
                float4 v = make_float4(0.f, 0.f, 0.f, 0.f);
                if (e < E) v = ((const float4*)(cur + (size_t)src[e] * HH))[c];
                x_t[cb ^ 1][c * 4 + 0][el] = v.x; x_t[cb ^ 1][c * 4 + 1][el] = v.y;
                x_t[cb ^ 1][c * 4 + 2][el] = v.z; x_t[cb ^ 1][c * 4 + 3][el] = v.w;
            }
        }

        float macc[4][2][4];
        #pragma unroll
        for (int m = 0; m < 4; ++m)
            #pragma unroll
            for (int nn = 0; nn < 2; ++nn)
                #pragma unroll
                for (int r = 0; r < 4; ++r) macc[m][nn][r] = 0.f;

        #pragma unroll
        for (int mh = 0; mh < 2; ++mh) {
            // A fragments for this 32-edge half (32 VGPR)
            bf16x8 af[2][4];
            #pragma unroll
            for (int mi = 0; mi < 2; ++mi)
                #pragma unroll
                for (int ks = 0; ks < 4; ++ks)
                    af[mi][ks] = *(const bf16x8*)(Rb + (size_t)(e0 + (mh * 2 + mi) * 16 + lo) * EDGE_H + ks * 32 + lq * 8);

            #pragma unroll
            for (int hh = 0; hh < 4; ++hh) {
                int h = wave * 4 + hh;
                #pragma unroll
                for (int mi = 0; mi < 2; ++mi) {
                    f32x4 acc[2];
                    acc[0] = (f32x4){b2v[hh][0], b2v[hh][0], b2v[hh][0], b2v[hh][0]};
                    acc[1] = (f32x4){b2v[hh][1], b2v[hh][1], b2v[hh][1], b2v[hh][1]};
                    #pragma unroll
                    for (int ks = 0; ks < 4; ++ks)
                        #pragma unroll
                        for (int nn = 0; nn < 2; ++nn)
                            acc[nn] = __builtin_amdgcn_mfma_f32_16x16x32_bf16(
                                af[mi][ks], bfrag[hh][nn][ks], acc[nn], 0, 0, 0);
                    const float4 xv = *(const float4*)&x_t[cb][h][(mh * 2 + mi) * 16 + lq * 4];
                    #pragma unroll
                    for (int nn = 0; nn < 2; ++nn) {
                        macc[mh * 2 + mi][nn][0] += xv.x * acc[nn][0];
                        macc[mh * 2 + mi][nn][1] += xv.y * acc[nn][1];
                        macc[mh * 2 + mi][nn][2] += xv.z * acc[nn][2];
                        macc[mh * 2 + mi][nn][3] += xv.w * acc[nn][3];
                    }
                }
            }
        }

        // cross-wave reduce over h-partitions: waves 0-3 write, 4-7 add
        if (wave < 4) {
            #pragma unroll
            for (int m = 0; m < 4; ++m)
                #pragma unroll
                for (int nn = 0; nn < 2; ++nn)
                    #pragma unroll
                    for (int r = 0; r < 4; ++r)
                        slots[wave][(m * 16 + lq * 4 + r) * 33 + nn * 16 + lo] = macc[m][nn][r];
        }
        __syncthreads();
        if (wave >= 4) {
            #pragma unroll
            for (int m = 0; m < 4; ++m)
                #pragma unroll
                for (int nn = 0; nn < 2; ++nn)
                    #pragma unroll
                    for (int r = 0; r < 4; ++r)
                        slots[wave - 4][(m * 16 + lq * 4 + r) * 33 + nn * 16 + lo] += macc[m][nn][r];
        }
        __syncthreads();

        // final sum of 4 slots + CSR store
        for (int i = t; i < ET8 * HH; i += 512) {
            int row = i >> 5, col = i & 31;
            float s = slots[0][row * 33 + col] + slots[1][row * 33 + col]
                    + slots[2][row * 33 + col] + slots[3][row * 33 + col];
            int e = e0 + row;
            if (e < E) outp[(size_t)pos[e] * HH + col] = s;
        }
        __syncthreads();   // slots + x_t[cb] safe to reuse
    }
}

// ---------------- node update: CSR gather-sum + conv/residual/lin1/relu ----------------
__global__ void k_node_update(const float* __restrict__ msg_sorted, const int* __restrict__ offsets,
                              const float* __restrict__ cur, const float* __restrict__ h0,
                              const float* __restrict__ conv_bias,
                              const float* __restrict__ lin1_w, const float* __restrict__ lin1_b,
                              float* __restrict__ nxt, int n) {
    __shared__ float t_s[8][HH + 1];
    __shared__ float w_s[HH][HH + 1];
    int t = threadIdx.x;
    for (int i = t; i < HH * HH; i += 256) w_s[i >> 5][i & 31] = lin1_w[i];
    int nl = t >> 5, h = t & 31;
    int nn = blockIdx.x * 8 + nl;
    float tv = 0.f;
    if (nn < n) {
        int s0 = offsets[nn], s1 = offsets[nn + 1];
        float s = 0.f;
        for (int i = s0; i < s1; ++i) s += msg_sorted[(size_t)i * HH + h];
        size_t idx = (size_t)nn * HH + h;
        float conv = s + cur[idx] + conv_bias[h];
        tv = 0.5f * conv + 0.5f * h0[idx];
    }
    t_s[nl][h] = tv;
    __syncthreads();
    if (nn < n) {
        const float BETA = 1.0f / 3.0f;
        float d = lin1_b[h];
        #pragma unroll
        for (int k = 0; k < HH; ++k) d += t_s[nl][k] * w_s[h][k];
        float v = BETA * d + (1.0f - BETA) * tv;
        nxt[(size_t)nn * HH + h] = fmaxf(v, 0.f);
    }
}

// ---------------- BN batch statistics ----------------
__global__ void k_bn_stats(const float* __restrict__ out, float* __restrict__ stats, int n) {
    int t = threadIdx.x;
    int h = t & 31, rg = t >> 5;
    float s = 0.f, s2 = 0.f;
    for (int nn = blockIdx.x * 8 + rg; nn < n; nn += gridDim.x * 8) {
        float v = out[(size_t)nn * HH + h];
        s += v; s2 += v * v;
    }
    __shared__ float sh[256], sh2[256];
    sh[t] = s; sh2[t] = s2;
    __syncthreads();
    if (rg == 0) {
        #pragma unroll
        for (int g = 1; g < 8; ++g) { s += sh[g * 32 + h]; s2 += sh2[g * 32 + h]; }
        atomicAdd(&stats[h], s);
        atomicAdd(&stats[32 + h], s2);
    }
}

// ---------------- BN apply + y_sigmoid head ----------------
__global__ void k_node_out(const float* __restrict__ out, const float* __restrict__ stats,
                           const float* __restrict__ gamma, const float* __restrict__ beta,
                           const float* __restrict__ ylin_w, const float* __restrict__ ylin_b,
                           float* __restrict__ y_bn, float* __restrict__ y_sig, int n) {
    int nn = blockIdx.x * blockDim.x + threadIdx.x;
    if (nn >= n) return;
    float inv_n = 1.f / (float)n;
    float yb[HH];
    #pragma unroll
    for (int h = 0; h < HH; ++h) {
        float mu = stats[h] * inv_n;
        float var = stats[32 + h] * inv_n - mu * mu;
        float v = out[(size_t)nn * HH + h];
        yb[h] = (v - mu) * rsqrtf(var + 1e-5f) * gamma[h] + beta[h];
    }
    #pragma unroll
    for (int h = 0; h < HH; ++h) y_bn[(size_t)nn * HH + h] = yb[h];
    #pragma unroll
    for (int c = 0; c < 3; ++c) {
        float d = ylin_b[c];
        #pragma unroll
        for (int h = 0; h < HH; ++h) d += yb[h] * ylin_w[c * HH + h];
        y_sig[(size_t)nn * 3 + c] = 1.f / (1.f + expf(-d));
    }
}

// ---------------- edge-hop head ----------------
__global__ void k_edge_hop(const float* __restrict__ y_bn, const int* __restrict__ sl,
                           const int* __restrict__ dl, const float* __restrict__ w,
                           const float* __restrict__ b, float* __restrict__ outp, int e2) {
    int e = blockIdx.x * blockDim.x + threadIdx.x;
    if (e >= e2) return;
    const float4* a = (const float4*)(y_bn + (size_t)sl[e] * HH);
    const float4* c = (const float4*)(y_bn + (size_t)dl[e] * HH);
    float d = b[0];
    #pragma unroll
    for (int q = 0; q < 8; ++q) {
        float4 av = a[q], cv = c[q];
        float4 wv = ((const float4*)w)[q];
        d += av.x * cv.x * wv.x + av.y * cv.y * wv.y + av.z * cv.z * wv.z + av.w * cv.w * wv.w;
    }
    outp[e] = 1.f / (1.f + expf(-d));
}

extern "C" void kernel_launch(void* const* d_in, const int* in_sizes, int n_in,
                              void* d_out, int out_size, void* d_ws, size_t ws_size,
                              hipStream_t stream) {
    const float* n_feat   = (const float*)d_in[0];
    const float* e_feat   = (const float*)d_in[1];
    const int*   src      = (const int*)d_in[2];
    const int*   dst      = (const int*)d_in[3];
    const int*   src_list = (const int*)d_in[4];
    const int*   dst_list = (const int*)d_in[5];
    const float* lin0_w   = (const float*)d_in[6];
    const float* lin0_b   = (const float*)d_in[7];
    const float* en1_w    = (const float*)d_in[8];
    const float* en1_b    = (const float*)d_in[9];
    const float* en2_w    = (const float*)d_in[10];
    const float* en2_b    = (const float*)d_in[11];
    const float* conv_bias= (const float*)d_in[12];
    const float* lin1_w   = (const float*)d_in[13];
    const float* lin1_b   = (const float*)d_in[14];
    const float* bn_gamma = (const float*)d_in[15];
    const float* bn_beta  = (const float*)d_in[16];
    const float* ylin_w   = (const float*)d_in[17];
    const float* ylin_b   = (const float*)d_in[18];
    const float* ylin2_w  = (const float*)d_in[19];
    const float* ylin2_b  = (const float*)d_in[20];

    int n  = in_sizes[0] / NODE_IN;
    int E  = in_sizes[1] / EDGE_IN;
    int e2 = in_sizes[4];
    int E_pad = (E + E_PAD_UNIT - 1) & ~(E_PAD_UNIT - 1);
    int tiles = E_pad / ET8;

    float* ws    = (float*)d_ws;
    size_t nh    = (size_t)n * HH;
    float* out_a = ws;
    float* out_b = out_a + nh;
    float* h0    = out_b + nh;
    float* y_bn  = h0 + nh;
    float* stats = y_bn + nh;                               // 64 floats
    float* msg_sorted = stats + 64;                         // E_pad*32 f32
    unsigned short* W2b = (unsigned short*)(msg_sorted + (size_t)E_pad * HH);
    unsigned short* Rb  = W2b + 1024 * EDGE_H;              // E_pad*128 bf16
    int* ibase   = (int*)(Rb + (size_t)E_pad * EDGE_H);
    int* deg     = ibase;
    int* offtmp  = deg + n;
    int* bsum    = offtmp + n;
    int* offsets = bsum + 256;
    int* cursor  = offsets + n + 1;
    int* pos     = cursor + n;

    int nb = (n + 255) / 256;

    k_prep_w2<<<(1024 * EDGE_H) / 256, 256, 0, stream>>>(en2_w, W2b);
    k_prep_r<<<E_pad / 256, 256, 0, stream>>>(e_feat, en1_w, en1_b, Rb, E, E_pad);
    k_lin0<<<(n + 7) / 8, 256, 0, stream>>>(n_feat, lin0_w, lin0_b, out_a, h0, n);

    k_zero_int<<<nb, 256, 0, stream>>>(deg, n);
    k_hist<<<(E + 255) / 256, 256, 0, stream>>>(dst, deg, E);
    k_scan1<<<nb, 256, 0, stream>>>(deg, offtmp, bsum, n);
    k_scan2<<<1, 256, 0, stream>>>(bsum, nb);
    k_scan3<<<(n + 256) / 256, 256, 0, stream>>>(offtmp, bsum, offsets, cursor, n, E);
    k_scatter_pos<<<(E + 255) / 256, 256, 0, stream>>>(dst, offsets, cursor, pos, E);

    const float* cur = out_a;
    float* nxt = out_b;
    for (int s = 0; s < 3; ++s) {
        k_edge_mfma8<<<256, 512, 0, stream>>>(
            Rb, W2b, en2_b, cur, src, pos, msg_sorted, E, tiles);
        k_node_update<<<(n + 7) / 8, 256, 0, stream>>>(
            msg_sorted, offsets, cur, h0, conv_bias, lin1_w, lin1_b, nxt, n);
        float* t = (float*)cur; cur = nxt; nxt = t;
    }

    hipMemsetAsync(stats, 0, 64 * sizeof(float), stream);
    k_bn_stats<<<256, 256, 0, stream>>>(cur, stats, n);

    float* y_sig = (float*)d_out;
    float* e_out = y_sig + (size_t)n * 3;
    k_node_out<<<(n + 255) / 256, 256, 0, stream>>>(
        cur, stats, bn_gamma, bn_beta, ylin_w, ylin_b, y_bn, y_sig, n);
    k_edge_hop<<<(e2 + 255) / 256, 256, 0, stream>>>(
        y_bn, src_list, dst_list, ylin2_w, ylin2_b, e_out, e2);
}

// Round 17
// 270.616 us; speedup vs baseline: 1.6478x; 1.1166x over previous
//
#include <hip/hip_runtime.h>
#include <hip/hip_bf16.h>
#include <math.h>

#define HH 32
#define NODE_IN 64
#define EDGE_IN 16
#define EDGE_H 128
#define M_TILE 256

typedef __attribute__((ext_vector_type(8))) short bf16x8;
typedef __attribute__((ext_vector_type(4))) float f32x4;

__device__ inline unsigned short f2bf(float f) {
    union { float f; unsigned int u; } v; v.f = f;
    unsigned int r = v.u + 0x7fff + ((v.u >> 16) & 1);   // RNE (inputs never NaN)
    return (unsigned short)(r >> 16);
}

__device__ inline void gload_lds16(const void* g, void* lds) {
    __builtin_amdgcn_global_load_lds(
        (const __attribute__((address_space(1))) void*)g,
        (__attribute__((address_space(3))) void*)lds, 16, 0, 0);
}

// ---------------- prep (B path): W2 f32 -> bf16, PERMUTED cols (c' = o*32+h) + chunk swizzle ----------------
// W2s[c'*128 + p*8 + sub] = bf16(en2_w[orig_row(c')*128 + (p^(c'&15))*8 + sub]),
// orig_row(c') = (c'&31)*32 + (c'>>5). GEMM over permuted cols stores Cb[e][o*32+h] directly.
__global__ void k_prep_w2p(const float* __restrict__ en2_w, unsigned short* __restrict__ W2s) {
    int i = blockIdx.x * 256 + threadIdx.x;
    int cp = i >> 7, q = i & 127;
    int p = q >> 3, sub = q & 7;
    int orow = ((cp & 31) << 5) | (cp >> 5);
    int c = p ^ (cp & 15);
    W2s[i] = f2bf(en2_w[orow * EDGE_H + c * 8 + sub]);
}

// ---------------- prep (fallback): W2 f32 -> bf16, chunk-swizzled, UNpermuted ----------------
__global__ void k_prep_w2(const float* __restrict__ en2_w, unsigned short* __restrict__ W2s) {
    int i = blockIdx.x * 256 + threadIdx.x;
    int r = i >> 7, q = i & 127;
    int p = q >> 3, sub = q & 7;
    int c = p ^ (r & 15);
    W2s[i] = f2bf(en2_w[r * EDGE_H + c * 8 + sub]);
}

// ---------------- prep: R = relu(e_feat @ en1_w^T + en1_b) -> bf16 [E_pad][128] ----------------
__global__ void __launch_bounds__(256, 4)
k_prep_r(const float* __restrict__ e_feat, const float* __restrict__ en1_w,
         const float* __restrict__ en1_b, unsigned short* __restrict__ Rb,
         int E, int E_pad) {
    int t = threadIdx.x, wave = t >> 6, l = t & 63;
    int lo = l & 15, lq = l >> 4;
    int ebase = blockIdx.x * 256 + wave * 64;

    bf16x8 bfrag[8];
    #pragma unroll
    for (int nt = 0; nt < 8; ++nt) {
        unsigned short br[8] = {0, 0, 0, 0, 0, 0, 0, 0};
        if (lq < 2) {
            const float* wr = en1_w + (nt * 16 + lo) * EDGE_IN + lq * 8;
            #pragma unroll
            for (int z = 0; z < 8; ++z) br[z] = f2bf(wr[z]);
        }
        bfrag[nt] = *(const bf16x8*)br;
    }
    float b1v[8];
    #pragma unroll
    for (int nt = 0; nt < 8; ++nt) b1v[nt] = en1_b[nt * 16 + lo];

    #pragma unroll
    for (int m = 0; m < 4; ++m) {
        int ea = ebase + m * 16 + lo;
        unsigned short ar[8] = {0, 0, 0, 0, 0, 0, 0, 0};
        if (lq < 2 && ea < E) {
            const float* er = e_feat + (size_t)ea * EDGE_IN + lq * 8;
            float4 v0 = ((const float4*)er)[0];
            float4 v1 = ((const float4*)er)[1];
            ar[0] = f2bf(v0.x); ar[1] = f2bf(v0.y); ar[2] = f2bf(v0.z); ar[3] = f2bf(v0.w);
            ar[4] = f2bf(v1.x); ar[5] = f2bf(v1.y); ar[6] = f2bf(v1.z); ar[7] = f2bf(v1.w);
        }
        bf16x8 af = *(const bf16x8*)ar;

        int erow = ebase + m * 16 + lq * 4;
        #pragma unroll
        for (int nt = 0; nt < 8; ++nt) {
            f32x4 acc = (f32x4){b1v[nt], b1v[nt], b1v[nt], b1v[nt]};
            acc = __builtin_amdgcn_mfma_f32_16x16x32_bf16(af, bfrag[nt], acc, 0, 0, 0);
            #pragma unroll
            for (int r = 0; r < 4; ++r)
                Rb[(size_t)(erow + r) * EDGE_H + nt * 16 + lo] = f2bf(fmaxf(acc[r], 0.f));
        }
    }
}

// ---------------- lin0 ----------------
__global__ void k_lin0(const float* __restrict__ nf, const float* __restrict__ w,
                       const float* __restrict__ b, float* __restrict__ out,
                       float* __restrict__ h0, int n) {
    __shared__ float nf_s[8][NODE_IN];
    __shared__ float w_s[HH][NODE_IN + 1];
    int t = threadIdx.x;
    for (int i = t; i < HH * NODE_IN; i += 256) w_s[i / NODE_IN][i % NODE_IN] = w[i];
    int n0 = blockIdx.x * 8;
    for (int i = t; i < 8 * NODE_IN; i += 256) {
        int nl = i / NODE_IN, k = i % NODE_IN;
        int nn = n0 + nl;
        nf_s[nl][k] = (nn < n) ? nf[(size_t)nn * NODE_IN + k] : 0.f;
    }
    __syncthreads();
    int nl = t >> 5, h = t & 31;
    int nn = n0 + nl;
    if (nn < n) {
        float acc = b[h];
        #pragma unroll
        for (int k = 0; k < NODE_IN; ++k) acc += nf_s[nl][k] * w_s[h][k];
        acc = fmaxf(acc, 0.f);
        out[(size_t)nn * HH + h] = acc;
        h0[(size_t)nn * HH + h] = acc;
    }
}

// ---------------- B path: one-time GEMM  Cb[e][o*32+h] = R[e]·W2^T + b2  (bf16) ----------------
// 512 thr / 8 waves x 32 edges; 8 groups of 4 col-slices; 2x32KB LDS double buffer,
// one vmcnt(0)+barrier per group (8 syncs total).
__global__ void __launch_bounds__(512, 2)
k_gemm_c(const unsigned short* __restrict__ Rb, const unsigned short* __restrict__ W2s,
         const float* __restrict__ b2, unsigned short* __restrict__ Cb) {
    __shared__ unsigned short w2buf[2][4 * 32 * EDGE_H];  // 2 x 32KB
    __shared__ float b2p_s[1024];
    int t = threadIdx.x, wave = t >> 6, l = t & 63;
    int lo = l & 15, lq = l >> 4;
    int e0 = blockIdx.x * M_TILE;

    for (int i = t; i < 1024; i += 512)
        b2p_s[i] = b2[((i & 31) << 5) | (i >> 5)];   // permuted: b2p[o*32+h]

    // A fragments: wave's 32 edge-rows, all K=128
    bf16x8 afrag[2][4];
    #pragma unroll
    for (int m = 0; m < 2; ++m)
        #pragma unroll
        for (int ks = 0; ks < 4; ++ks)
            afrag[m][ks] = *(const bf16x8*)(Rb + (size_t)(e0 + wave * 32 + m * 16 + lo) * EDGE_H + ks * 32 + lq * 8);

    // prologue: stage group 0 (4 slices = 32KB) into buf 0
    #pragma unroll
    for (int k = 0; k < 4; ++k)
        gload_lds16(W2s + k * 4096 + t * 8, &w2buf[0][k * 4096 + t * 8]);

    asm volatile("s_waitcnt lgkmcnt(0)" ::: "memory");   // b2p_s writes visible pre-barrier

    for (int g = 0; g < 8; ++g) {
        asm volatile("s_waitcnt vmcnt(0)" ::: "memory");
        __builtin_amdgcn_s_barrier();
        if (g + 1 < 8) {
            #pragma unroll
            for (int k = 0; k < 4; ++k)
                gload_lds16(W2s + (size_t)(g + 1) * 16384 + k * 4096 + t * 8,
                            &w2buf[(g + 1) & 1][k * 4096 + t * 8]);
        }
        const unsigned short* wb = w2buf[g & 1];

        #pragma unroll
        for (int cgl = 0; cgl < 4; ++cgl) {
            int cg = g * 4 + cgl;
            bf16x8 bfrag[2][4];
            #pragma unroll
            for (int nn = 0; nn < 2; ++nn)
                #pragma unroll
                for (int ks = 0; ks < 4; ++ks)
                    bfrag[nn][ks] = *(const bf16x8*)&wb[cgl * 4096 + (nn * 16 + lo) * EDGE_H + (((ks * 4 + lq) ^ lo) * 8)];

            f32x4 acc[2][2];
            #pragma unroll
            for (int nn = 0; nn < 2; ++nn) {
                float bb = b2p_s[cg * 32 + nn * 16 + lo];
                acc[0][nn] = (f32x4){bb, bb, bb, bb};
                acc[1][nn] = (f32x4){bb, bb, bb, bb};
            }
            #pragma unroll
            for (int ks = 0; ks < 4; ++ks)
                #pragma unroll
                for (int m = 0; m < 2; ++m)
                    #pragma unroll
                    for (int nn = 0; nn < 2; ++nn)
                        acc[m][nn] = __builtin_amdgcn_mfma_f32_16x16x32_bf16(
                            afrag[m][ks], bfrag[nn][ks], acc[m][nn], 0, 0, 0);

            // store this 32-col slice (cols = cg*32 + nn*16 + lo), rows = wave's edges
            #pragma unroll
            for (int m = 0; m < 2; ++m) {
                int erow = e0 + wave * 32 + m * 16 + lq * 4;
                #pragma unroll
                for (int nn = 0; nn < 2; ++nn)
                    #pragma unroll
                    for (int r = 0; r < 4; ++r)
                        Cb[(size_t)(erow + r) * 1024 + cg * 32 + nn * 16 + lo] = f2bf(acc[m][nn][r]);
            }
        }
    }
}

// ---------------- B path: per-step edge kernel (memory-bound stream over Cb) ----------------
// thread <-> (edge, o); msg[e,o] = sum_h x[e,h]*Cb[e][o*32+h]; atomic scatter to agg.
__global__ void __launch_bounds__(256)
k_step(const unsigned short* __restrict__ Cb, const float* __restrict__ cur,
       const int* __restrict__ src, const int* __restrict__ dst,
       float* __restrict__ agg, int E) {
    __shared__ float x_s[8][33];
    int t = threadIdx.x;
    {
        int ee = blockIdx.x * 8 + (t >> 5);
        int h = t & 31;
        x_s[t >> 5][h] = (ee < E) ? cur[(size_t)src[ee] * HH + h] : 0.f;
    }
    __syncthreads();
    int el = t >> 5, o = t & 31;
    int e = blockIdx.x * 8 + el;
    if (e >= E) return;
    const uint4* cp = (const uint4*)(Cb + (size_t)e * 1024 + o * 32);
    const float* xr = x_s[el];
    float s = 0.f;
    #pragma unroll
    for (int w4 = 0; w4 < 4; ++w4) {
        uint4 c = cp[w4];
        unsigned int uu[4] = {c.x, c.y, c.z, c.w};
        #pragma unroll
        for (int q = 0; q < 4; ++q) {
            unsigned int u = uu[q];
            union { unsigned int i; float f; } flo, fhi;
            flo.i = u << 16;
            fhi.i = u & 0xffff0000u;
            int h = w4 * 8 + q * 2;
            s += xr[h] * flo.f + xr[h + 1] * fhi.f;
        }
    }
    atomicAdd(&agg[(size_t)dst[e] * HH + o], s);
}

// ---------------- B path: node update from agg ----------------
__global__ void k_node_update_agg(const float* __restrict__ agg,
                                  const float* __restrict__ cur, const float* __restrict__ h0,
                                  const float* __restrict__ conv_bias,
                                  const float* __restrict__ lin1_w, const float* __restrict__ lin1_b,
                                  float* __restrict__ nxt, int n) {
    __shared__ float t_s[8][HH + 1];
    __shared__ float w_s[HH][HH + 1];
    int t = threadIdx.x;
    for (int i = t; i < HH * HH; i += 256) w_s[i >> 5][i & 31] = lin1_w[i];
    int nl = t >> 5, h = t & 31;
    int nn = blockIdx.x * 8 + nl;
    float tv = 0.f;
    if (nn < n) {
        size_t idx = (size_t)nn * HH + h;
        float conv = agg[idx] + cur[idx] + conv_bias[h];
        tv = 0.5f * conv + 0.5f * h0[idx];
    }
    t_s[nl][h] = tv;
    __syncthreads();
    if (nn < n) {
        const float BETA = 1.0f / 3.0f;
        float d = lin1_b[h];
        #pragma unroll
        for (int k = 0; k < HH; ++k) d += t_s[nl][k] * w_s[h][k];
        float v = BETA * d + (1.0f - BETA) * tv;
        nxt[(size_t)nn * HH + h] = fmaxf(v, 0.f);
    }
}

// ---------------- CSR build (fallback path) ----------------
__global__ void k_zero_int(int* __restrict__ p, int n) {
    int i = blockIdx.x * 256 + threadIdx.x;
    if (i < n) p[i] = 0;
}
__global__ void k_hist(const int* __restrict__ dst, int* __restrict__ deg, int E) {
    int e = blockIdx.x * 256 + threadIdx.x;
    if (e < E) atomicAdd(&deg[dst[e]], 1);
}
__global__ void k_scan1(const int* __restrict__ deg, int* __restrict__ offtmp,
                        int* __restrict__ bsum, int n) {
    __shared__ int sh[256];
    int tid = threadIdx.x;
    int i = blockIdx.x * 256 + tid;
    int v = (i < n) ? deg[i] : 0;
    sh[tid] = v;
    __syncthreads();
    for (int d = 1; d < 256; d <<= 1) {
        int add = (tid >= d) ? sh[tid - d] : 0;
        __syncthreads();
        sh[tid] += add;
        __syncthreads();
    }
    if (i < n) offtmp[i] = sh[tid] - v;
    if (tid == 255) bsum[blockIdx.x] = sh[255];
}
__global__ void k_scan2(int* __restrict__ bsum, int nb) {
    __shared__ int sh[256];
    int tid = threadIdx.x;
    int v = (tid < nb) ? bsum[tid] : 0;
    sh[tid] = v;
    __syncthreads();
    for (int d = 1; d < 256; d <<= 1) {
        int add = (tid >= d) ? sh[tid - d] : 0;
        __syncthreads();
        sh[tid] += add;
        __syncthreads();
    }
    if (tid < nb) bsum[tid] = sh[tid] - v;
}
__global__ void k_scan3(const int* __restrict__ offtmp, const int* __restrict__ bsum,
                        int* __restrict__ offsets, int* __restrict__ cursor, int n, int E) {
    int i = blockIdx.x * 256 + threadIdx.x;
    if (i < n) { offsets[i] = offtmp[i] + bsum[i >> 8]; cursor[i] = 0; }
    if (i == n) offsets[n] = E;
}
__global__ void k_scatter_pos(const int* __restrict__ dst, const int* __restrict__ offsets,
                              int* __restrict__ cursor, int* __restrict__ pos, int E) {
    int e = blockIdx.x * 256 + threadIdx.x;
    if (e < E) pos[e] = offsets[dst[e]] + atomicAdd(&cursor[dst[e]], 1);
}

// ---------------- fallback: MFMA edge kernel v4 (proven 51us) ----------------
__global__ void __launch_bounds__(512, 2)
k_edge_mfma4(const unsigned short* __restrict__ Rb, const unsigned short* __restrict__ W2s,
             const float* __restrict__ b2, const float* __restrict__ cur,
             const int* __restrict__ src, const int* __restrict__ pos,
             float* __restrict__ outp, int E) {
    __shared__ unsigned short w2buf[4][32 * EDGE_H];
    __shared__ float x_t[HH][M_TILE];
    __shared__ float b2_s[HH * HH];
    int t = threadIdx.x, wave = t >> 6, l = t & 63;
    int lo = l & 15, lq = l >> 4;
    int e0 = blockIdx.x * M_TILE;

    for (int i = t; i < HH * HH; i += 512) b2_s[i] = b2[i];

    for (int i = t; i < M_TILE * 8; i += 512) {
        int el = i >> 3, c = i & 7;
        int e = e0 + el;
        float4 v = make_float4(0.f, 0.f, 0.f, 0.f);
        if (e < E) v = ((const float4*)(cur + (size_t)src[e] * HH))[c];
        x_t[c * 4 + 0][el] = v.x; x_t[c * 4 + 1][el] = v.y;
        x_t[c * 4 + 2][el] = v.z; x_t[c * 4 + 3][el] = v.w;
    }

    bf16x8 afrag[2][4];
    #pragma unroll
    for (int m = 0; m < 2; ++m)
        #pragma unroll
        for (int ks = 0; ks < 4; ++ks)
            afrag[m][ks] = *(const bf16x8*)(Rb + (size_t)(e0 + wave * 32 + m * 16 + lo) * EDGE_H + ks * 32 + lq * 8);

    #pragma unroll
    for (int s = 0; s < 3; ++s)
        gload_lds16(W2s + (size_t)s * 4096 + t * 8, &w2buf[s][t * 8]);

    asm volatile("s_waitcnt lgkmcnt(0)" ::: "memory");

    float macc[2][2][4];
    #pragma unroll
    for (int m = 0; m < 2; ++m)
        #pragma unroll
        for (int nn = 0; nn < 2; ++nn)
            #pragma unroll
            for (int r = 0; r < 4; ++r) macc[m][nn][r] = 0.f;

    #pragma unroll 4
    for (int h = 0; h < HH; ++h) {
        if (h < 30)       asm volatile("s_waitcnt vmcnt(2)" ::: "memory");
        else if (h == 30) asm volatile("s_waitcnt vmcnt(1)" ::: "memory");
        else              asm volatile("s_waitcnt vmcnt(0)" ::: "memory");
        __builtin_amdgcn_s_barrier();
        if (h + 3 < HH)
            gload_lds16(W2s + (size_t)(h + 3) * 4096 + t * 8, &w2buf[(h + 3) & 3][t * 8]);

        const unsigned short* wb = w2buf[h & 3];
        bf16x8 bfrag[2][4];
        #pragma unroll
        for (int nn = 0; nn < 2; ++nn)
            #pragma unroll
            for (int ks = 0; ks < 4; ++ks)
                bfrag[nn][ks] = *(const bf16x8*)&wb[(nn * 16 + lo) * EDGE_H + (((ks * 4 + lq) ^ lo) * 8)];

        f32x4 acc[2][2];
        #pragma unroll
        for (int nn = 0; nn < 2; ++nn) {
            float bb = b2_s[h * HH + nn * 16 + lo];
            acc[0][nn] = (f32x4){bb, bb, bb, bb};
            acc[1][nn] = (f32x4){bb, bb, bb, bb};
        }
        #pragma unroll
        for (int ks = 0; ks < 4; ++ks)
            #pragma unroll
            for (int m = 0; m < 2; ++m)
                #pragma unroll
                for (int nn = 0; nn < 2; ++nn)
                    acc[m][nn] = __builtin_amdgcn_mfma_f32_16x16x32_bf16(
                        afrag[m][ks], bfrag[nn][ks], acc[m][nn], 0, 0, 0);

        #pragma unroll
        for (int m = 0; m < 2; ++m) {
            const float4 xv = *(const float4*)&x_t[h][wave * 32 + m * 16 + lq * 4];
            #pragma unroll
            for (int nn = 0; nn < 2; ++nn) {
                macc[m][nn][0] += xv.x * acc[m][nn][0];
                macc[m][nn][1] += xv.y * acc[m][nn][1];
                macc[m][nn][2] += xv.z * acc[m][nn][2];
                macc[m][nn][3] += xv.w * acc[m][nn][3];
            }
        }
    }

    #pragma unroll
    for (int m = 0; m < 2; ++m) {
        int ebase = e0 + wave * 32 + m * 16 + lq * 4;
        const int4 p4 = *(const int4*)&pos[ebase];
        int pr[4] = { p4.x, p4.y, p4.z, p4.w };
        #pragma unroll
        for (int r = 0; r < 4; ++r) {
            if (ebase + r < E) {
                outp[(size_t)pr[r] * HH + lo]      = macc[m][0][r];
                outp[(size_t)pr[r] * HH + 16 + lo] = macc[m][1][r];
            }
        }
    }
}

// ---------------- fallback: node update with CSR gather ----------------
__global__ void k_node_update_csr(const float* __restrict__ msg_sorted, const int* __restrict__ offsets,
                                  const float* __restrict__ cur, const float* __restrict__ h0,
                                  const float* __restrict__ conv_bias,
                                  const float* __restrict__ lin1_w, const float* __restrict__ lin1_b,
                                  float* __restrict__ nxt, int n) {
    __shared__ float t_s[8][HH + 1];
    __shared__ float w_s[HH][HH + 1];
    int t = threadIdx.x;
    for (int i = t; i < HH * HH; i += 256) w_s[i >> 5][i & 31] = lin1_w[i];
    int nl = t >> 5, h = t & 31;
    int nn = blockIdx.x * 8 + nl;
    float tv = 0.f;
    if (nn < n) {
        int s0 = offsets[nn], s1 = offsets[nn + 1];
        float s = 0.f;
        for (int i = s0; i < s1; ++i) s += msg_sorted[(size_t)i * HH + h];
        size_t idx = (size_t)nn * HH + h;
        float conv = s + cur[idx] + conv_bias[h];
        tv = 0.5f * conv + 0.5f * h0[idx];
    }
    t_s[nl][h] = tv;
    __syncthreads();
    if (nn < n) {
        const float BETA = 1.0f / 3.0f;
        float d = lin1_b[h];
        #pragma unroll
        for (int k = 0; k < HH; ++k) d += t_s[nl][k] * w_s[h][k];
        float v = BETA * d + (1.0f - BETA) * tv;
        nxt[(size_t)nn * HH + h] = fmaxf(v, 0.f);
    }
}

// ---------------- BN batch statistics ----------------
__global__ void k_bn_stats(const float* __restrict__ out, float* __restrict__ stats, int n) {
    int t = threadIdx.x;
    int h = t & 31, rg = t >> 5;
    float s = 0.f, s2 = 0.f;
    for (int nn = blockIdx.x * 8 + rg; nn < n; nn += gridDim.x * 8) {
        float v = out[(size_t)nn * HH + h];
        s += v; s2 += v * v;
    }
    __shared__ float sh[256], sh2[256];
    sh[t] = s; sh2[t] = s2;
    __syncthreads();
    if (rg == 0) {
        #pragma unroll
        for (int g = 1; g < 8; ++g) { s += sh[g * 32 + h]; s2 += sh2[g * 32 + h]; }
        atomicAdd(&stats[h], s);
        atomicAdd(&stats[32 + h], s2);
    }
}

// ---------------- BN apply + y_sigmoid head ----------------
__global__ void k_node_out(const float* __restrict__ out, const float* __restrict__ stats,
                           const float* __restrict__ gamma, const float* __restrict__ beta,
                           const float* __restrict__ ylin_w, const float* __restrict__ ylin_b,
                           float* __restrict__ y_bn, float* __restrict__ y_sig, int n) {
    int nn = blockIdx.x * blockDim.x + threadIdx.x;
    if (nn >= n) return;
    float inv_n = 1.f / (float)n;
    float yb[HH];
    #pragma unroll
    for (int h = 0; h < HH; ++h) {
        float mu = stats[h] * inv_n;
        float var = stats[32 + h] * inv_n - mu * mu;
        float v = out[(size_t)nn * HH + h];
        yb[h] = (v - mu) * rsqrtf(var + 1e-5f) * gamma[h] + beta[h];
    }
    #pragma unroll
    for (int h = 0; h < HH; ++h) y_bn[(size_t)nn * HH + h] = yb[h];
    #pragma unroll
    for (int c = 0; c < 3; ++c) {
        float d = ylin_b[c];
        #pragma unroll
        for (int h = 0; h < HH; ++h) d += yb[h] * ylin_w[c * HH + h];
        y_sig[(size_t)nn * 3 + c] = 1.f / (1.f + expf(-d));
    }
}

// ---------------- edge-hop head ----------------
__global__ void k_edge_hop(const float* __restrict__ y_bn, const int* __restrict__ sl,
                           const int* __restrict__ dl, const float* __restrict__ w,
                           const float* __restrict__ b, float* __restrict__ outp, int e2) {
    int e = blockIdx.x * blockDim.x + threadIdx.x;
    if (e >= e2) return;
    const float4* a = (const float4*)(y_bn + (size_t)sl[e] * HH);
    const float4* c = (const float4*)(y_bn + (size_t)dl[e] * HH);
    float d = b[0];
    #pragma unroll
    for (int q = 0; q < 8; ++q) {
        float4 av = a[q], cv = c[q];
        float4 wv = ((const float4*)w)[q];
        d += av.x * cv.x * wv.x + av.y * cv.y * wv.y + av.z * cv.z * wv.z + av.w * cv.w * wv.w;
    }
    outp[e] = 1.f / (1.f + expf(-d));
}

extern "C" void kernel_launch(void* const* d_in, const int* in_sizes, int n_in,
                              void* d_out, int out_size, void* d_ws, size_t ws_size,
                              hipStream_t stream) {
    const float* n_feat   = (const float*)d_in[0];
    const float* e_feat   = (const float*)d_in[1];
    const int*   src      = (const int*)d_in[2];
    const int*   dst      = (const int*)d_in[3];
    const int*   src_list = (const int*)d_in[4];
    const int*   dst_list = (const int*)d_in[5];
    const float* lin0_w   = (const float*)d_in[6];
    const float* lin0_b   = (const float*)d_in[7];
    const float* en1_w    = (const float*)d_in[8];
    const float* en1_b    = (const float*)d_in[9];
    const float* en2_w    = (const float*)d_in[10];
    const float* en2_b    = (const float*)d_in[11];
    const float* conv_bias= (const float*)d_in[12];
    const float* lin1_w   = (const float*)d_in[13];
    const float* lin1_b   = (const float*)d_in[14];
    const float* bn_gamma = (const float*)d_in[15];
    const float* bn_beta  = (const float*)d_in[16];
    const float* ylin_w   = (const float*)d_in[17];
    const float* ylin_b   = (const float*)d_in[18];
    const float* ylin2_w  = (const float*)d_in[19];
    const float* ylin2_b  = (const float*)d_in[20];

    int n  = in_sizes[0] / NODE_IN;
    int E  = in_sizes[1] / EDGE_IN;
    int e2 = in_sizes[4];
    int E_pad = (E + M_TILE - 1) & ~(M_TILE - 1);

    float* ws = (float*)d_ws;
    size_t nh = (size_t)n * HH;

    size_t needed = ((size_t)5 * nh + 64) * 4           // out_a,out_b,h0,y_bn,stats,agg
                  + (size_t)1024 * EDGE_H * 2           // W2s
                  + (size_t)E_pad * EDGE_H * 2          // Rb
                  + (size_t)E_pad * 1024 * 2;           // Cb

    if (ws_size >= needed) {
        // ---------------- B path: materialized C, streamed 3x ----------------
        float* out_a = ws;
        float* out_b = out_a + nh;
        float* h0    = out_b + nh;
        float* y_bn  = h0 + nh;
        float* stats = y_bn + nh;                            // 64
        float* agg   = stats + 64;                           // nh
        unsigned short* W2s = (unsigned short*)(agg + nh);   // 1024*128
        unsigned short* Rb  = W2s + 1024 * EDGE_H;           // E_pad*128
        unsigned short* Cb  = Rb + (size_t)E_pad * EDGE_H;   // E_pad*1024

        k_prep_w2p<<<(1024 * EDGE_H) / 256, 256, 0, stream>>>(en2_w, W2s);
        k_prep_r<<<E_pad / 256, 256, 0, stream>>>(e_feat, en1_w, en1_b, Rb, E, E_pad);
        k_lin0<<<(n + 7) / 8, 256, 0, stream>>>(n_feat, lin0_w, lin0_b, out_a, h0, n);

        k_gemm_c<<<E_pad / M_TILE, 512, 0, stream>>>(Rb, W2s, en2_b, Cb);

        const float* cur = out_a;
        float* nxt = out_b;
        for (int s = 0; s < 3; ++s) {
            hipMemsetAsync(agg, 0, nh * sizeof(float), stream);
            k_step<<<(E + 7) / 8, 256, 0, stream>>>(Cb, cur, src, dst, agg, E);
            k_node_update_agg<<<(n + 7) / 8, 256, 0, stream>>>(
                agg, cur, h0, conv_bias, lin1_w, lin1_b, nxt, n);
            float* t = (float*)cur; cur = nxt; nxt = t;
        }

        hipMemsetAsync(stats, 0, 64 * sizeof(float), stream);
        k_bn_stats<<<256, 256, 0, stream>>>(cur, stats, n);

        float* y_sig = (float*)d_out;
        float* e_out = y_sig + (size_t)n * 3;
        k_node_out<<<(n + 255) / 256, 256, 0, stream>>>(
            cur, stats, bn_gamma, bn_beta, ylin_w, ylin_b, y_bn, y_sig, n);
        k_edge_hop<<<(e2 + 255) / 256, 256, 0, stream>>>(
            y_bn, src_list, dst_list, ylin2_w, ylin2_b, e_out, e2);
    } else {
        // ---------------- fallback: proven R7 path ----------------
        float* out_a = ws;
        float* out_b = out_a + nh;
        float* h0    = out_b + nh;
        float* y_bn  = h0 + nh;
        float* stats = y_bn + nh;
        float* msg_sorted = stats + 64;
        unsigned short* W2s = (unsigned short*)(msg_sorted + (size_t)E_pad * HH);
        unsigned short* Rb  = W2s + 1024 * EDGE_H;
        int* ibase   = (int*)(Rb + (size_t)E_pad * EDGE_H);
        int* deg     = ibase;
        int* offtmp  = deg + n;
        int* bsum    = offtmp + n;
        int* offsets = bsum + 256;
        int* cursor  = offsets + n + 1;
        int* pos     = cursor + n;

        int nb = (n + 255) / 256;

        k_prep_w2<<<(1024 * EDGE_H) / 256, 256, 0, stream>>>(en2_w, W2s);
        k_prep_r<<<E_pad / 256, 256, 0, stream>>>(e_feat, en1_w, en1_b, Rb, E, E_pad);
        k_lin0<<<(n + 7) / 8, 256, 0, stream>>>(n_feat, lin0_w, lin0_b, out_a, h0, n);

        k_zero_int<<<nb, 256, 0, stream>>>(deg, n);
        k_hist<<<(E + 255) / 256, 256, 0, stream>>>(dst, deg, E);
        k_scan1<<<nb, 256, 0, stream>>>(deg, offtmp, bsum, n);
        k_scan2<<<1, 256, 0, stream>>>(bsum, nb);
        k_scan3<<<(n + 256) / 256, 256, 0, stream>>>(offtmp, bsum, offsets, cursor, n, E);
        k_scatter_pos<<<(E + 255) / 256, 256, 0, stream>>>(dst, offsets, cursor, pos, E);

        const float* cur = out_a;
        float* nxt = out_b;
        for (int s = 0; s < 3; ++s) {
            k_edge_mfma4<<<E_pad / M_TILE, 512, 0, stream>>>(
                Rb, W2s, en2_b, cur, src, pos, msg_sorted, E);
            k_node_update_csr<<<(n + 7) / 8, 256, 0, stream>>>(
                msg_sorted, offsets, cur, h0, conv_bias, lin1_w, lin1_b, nxt, n);
            float* t = (float*)cur; cur = nxt; nxt = t;
        }

        hipMemsetAsync(stats, 0, 64 * sizeof(float), stream);
        k_bn_stats<<<256, 256, 0, stream>>>(cur, stats, n);

        float* y_sig = (float*)d_out;
        float* e_out = y_sig + (size_t)n * 3;
        k_node_out<<<(n + 255) / 256, 256, 0, stream>>>(
            cur, stats, bn_gamma, bn_beta, ylin_w, ylin_b, y_bn, y_sig, n);
        k_edge_hop<<<(e2 + 255) / 256, 256, 0, stream>>>(
            y_bn, src_list, dst_list, ylin2_w, ylin2_b, e_out, e2);
    }
}